// Round 1
// baseline (1092.077 us; speedup 1.0000x reference)
//
#include <hip/hip_runtime.h>
#include <hip/hip_bf16.h>

typedef __attribute__((ext_vector_type(4))) float f32x4;
typedef __attribute__((ext_vector_type(8))) short short8;

__device__ inline unsigned short f2bf(float f) {
    union { float f; unsigned int u; } v; v.f = f;
    unsigned int u = v.u;
    unsigned int r = (u + 0x7fffu + ((u >> 16) & 1u)) >> 16;
    return (unsigned short)r;
}

// ---------------- degree / CSR build ----------------

__global__ __launch_bounds__(256) void deg_count_k(const int* __restrict__ dst, int* __restrict__ deg, int e) {
    int i = blockIdx.x * 256 + threadIdx.x;
    if (i < e) atomicAdd(&deg[dst[i]], 1);
}

__global__ __launch_bounds__(256) void dinv_k(const int* __restrict__ deg, float* __restrict__ dinv, int n) {
    int i = blockIdx.x * 256 + threadIdx.x;
    if (i < n) dinv[i] = rsqrtf(fmaxf((float)deg[i], 1.0f));
}

__global__ __launch_bounds__(1024) void scan_rowptr_k(const int* __restrict__ deg, int* __restrict__ rowptr,
                                                      int* __restrict__ cursor, int n) {
    __shared__ int part[1024];
    int t = threadIdx.x;
    int chunk = (n + 1023) / 1024;
    int b = t * chunk;
    int en = b + chunk; if (en > n) en = n;
    int s = 0;
    for (int i = b; i < en; ++i) s += deg[i];
    part[t] = s;
    __syncthreads();
    for (int off = 1; off < 1024; off <<= 1) {
        int v = (t >= off) ? part[t - off] : 0;
        __syncthreads();
        part[t] += v;
        __syncthreads();
    }
    int base = (t == 0) ? 0 : part[t - 1];
    for (int i = b; i < en; ++i) {
        rowptr[i] = base; cursor[i] = base;
        base += deg[i];
    }
    if (t == 1023) rowptr[n] = base;
}

__global__ __launch_bounds__(256) void scatter_k(const int* __restrict__ src, const int* __restrict__ dst,
                                                 int* __restrict__ cursor, int* __restrict__ csrc, int e) {
    int i = blockIdx.x * 256 + threadIdx.x;
    if (i < e) {
        int p = atomicAdd(&cursor[dst[i]], 1);
        csrc[p] = src[i];
    }
}

// ---------------- SpMM (normalized adjacency), CSR by dst ----------------
// out[d][:] = dinv[d] * sum_{s in in(d)} dinv[s] * x[s][:]

__global__ __launch_bounds__(256) void spmm_csr_k(const float* __restrict__ x, const int* __restrict__ rowptr,
                                                  const int* __restrict__ csrc, const float* __restrict__ dinv,
                                                  float* __restrict__ out, int n) {
    int lane = threadIdx.x & 63;
    int wave = threadIdx.x >> 6;
    int node = blockIdx.x * 4 + wave;
    if (node >= n) return;
    int beg = rowptr[node], end = rowptr[node + 1];
    float a0 = 0.f, a1 = 0.f;
    for (int i = beg; i < end; ++i) {
        int s = csrc[i];
        float w = dinv[s];
        float2 v = ((const float2*)(x + (size_t)s * 128))[lane];
        a0 += w * v.x;
        a1 += w * v.y;
    }
    float dd = dinv[node];
    float2 o; o.x = a0 * dd; o.y = a1 * dd;
    ((float2*)(out + (size_t)node * 128))[lane] = o;
}

// ---------------- weight pack into MFMA B-fragment order (bf16) ----------------
// wpack layout: [(ks*NF + f)*512 + lane*8 + j] = W'[ks*32 + (lane>>4)*8 + j][f*16 + (lane&15)]
// cheb mode: W' = [W0 - W2 ; -W1 ; 2*W2]  (K=384); else plain [K][N] row-major.

__global__ __launch_bounds__(256) void pack_w_k(const float* __restrict__ W, unsigned short* __restrict__ out,
                                                int K, int N, int cheb) {
    int id = blockIdx.x * 256 + threadIdx.x;
    int total = (K / 32) * (N / 16) * 64;
    if (id >= total) return;
    int lane = id & 63;
    int t2 = id >> 6;
    int nf = N / 16;
    int f = t2 % nf;
    int ks = t2 / nf;
    int col = f * 16 + (lane & 15);
    int kbase = ks * 32 + ((lane >> 4) * 8);
    for (int j = 0; j < 8; ++j) {
        int kg = kbase + j;
        float v;
        if (cheb) {
            int t = kg >> 7, kk = kg & 127;
            const float* W0 = W;
            const float* Wb = W + 16384;
            const float* Wc = W + 32768;
            float w0 = W0[kk * 128 + col], wb = Wb[kk * 128 + col], wc = Wc[kk * 128 + col];
            v = (t == 0) ? (w0 - wc) : (t == 1) ? (-wb) : (2.0f * wc);
        } else {
            v = W[(size_t)kg * N + col];
        }
        out[(size_t)id * 8 + j] = f2bf(v);
    }
}

// ---------------- MFMA GEMM: C[n x NF*16] = [s0|s1|s2](bf16) @ Wpack + bias ----------------
// No LDS: A-fragments loaded directly (each element read once), B-fragments from packed L2-resident weights.

template<int KSTEPS, int NF, bool RELU, bool RES>
__global__ __launch_bounds__(256) void gemm_k(const float* __restrict__ s0, const float* __restrict__ s1,
                                              const float* __restrict__ s2, const unsigned short* __restrict__ wp,
                                              const float* __restrict__ bias, const float* __restrict__ resid,
                                              float* __restrict__ out, int n) {
    int lane = threadIdx.x & 63;
    int wave = threadIdx.x >> 6;
    int row0 = blockIdx.x * 64 + wave * 16;
    if (row0 >= n) return;
    int rowA = row0 + (lane & 15);
    int kg = (lane >> 4) * 8;

    f32x4 acc[NF];
#pragma unroll
    for (int f = 0; f < NF; ++f) acc[f] = (f32x4)(0.0f);

#pragma unroll
    for (int ks = 0; ks < KSTEPS; ++ks) {
        const float* sp;
        int kk;
        if (KSTEPS == 12) {
            sp = (ks < 4) ? s0 : ((ks < 8) ? s1 : s2);
            kk = (ks & 3) * 32 + kg;
        } else {
            sp = s0;
            kk = ks * 32 + kg;
        }
        const f32x4* ap = (const f32x4*)(sp + (size_t)rowA * 128 + kk);
        f32x4 a0 = ap[0], a1 = ap[1];
        union { unsigned short u[8]; short8 v; } af;
#pragma unroll
        for (int j = 0; j < 4; ++j) { af.u[j] = f2bf(a0[j]); af.u[4 + j] = f2bf(a1[j]); }
#pragma unroll
        for (int f = 0; f < NF; ++f) {
            short8 b = *(const short8*)(wp + ((size_t)(ks * NF + f) * 512 + lane * 8));
            acc[f] = __builtin_amdgcn_mfma_f32_16x16x32_bf16(af.v, b, acc[f], 0, 0, 0);
        }
    }

    int colb = lane & 15;
    int rowD = row0 + ((lane >> 4) << 2);
#pragma unroll
    for (int f = 0; f < NF; ++f) {
        int c = f * 16 + colb;
        float bv = bias[c];
#pragma unroll
        for (int r = 0; r < 4; ++r) {
            int row = rowD + r;
            float v = acc[f][r] + bv;
            if (RELU) v = fmaxf(v, 0.0f);
            if (RES) v += resid[(size_t)row * 128 + c];
            out[(size_t)row * (NF * 16) + c] = v;
        }
    }
}

// ---------------- BatchNorm (training-mode batch stats) ----------------

__global__ __launch_bounds__(256) void bn_stats_k(const float* __restrict__ x, float* __restrict__ gsum,
                                                  float* __restrict__ gsqs, int n) {
    __shared__ float s1[256], s2[256];
    int c = threadIdx.x & 127;
    int h = threadIdx.x >> 7;
    int r0 = blockIdx.x * 256;
    int rend = r0 + 256; if (rend > n) rend = n;
    float a = 0.f, b = 0.f;
    for (int r = r0 + h; r < rend; r += 2) {
        float v = x[(size_t)r * 128 + c];
        a += v; b += v * v;
    }
    s1[threadIdx.x] = a; s2[threadIdx.x] = b;
    __syncthreads();
    if (threadIdx.x < 128) {
        a = s1[threadIdx.x] + s1[threadIdx.x + 128];
        b = s2[threadIdx.x] + s2[threadIdx.x + 128];
        atomicAdd(&gsum[c], a);
        atomicAdd(&gsqs[c], b);
    }
}

__global__ __launch_bounds__(256) void bn_apply_k(float* __restrict__ x, const float* __restrict__ gsum,
                                                  const float* __restrict__ gsqs, const float* __restrict__ gamma,
                                                  const float* __restrict__ beta, int n, float inv_n) {
    int i = blockIdx.x * 256 + threadIdx.x;   // over n*32 float4s
    if (i >= n * 32) return;
    int c4 = (i & 31) * 4;
    f32x4 v = ((f32x4*)x)[i];
#pragma unroll
    for (int j = 0; j < 4; ++j) {
        int c = c4 + j;
        float mu = gsum[c] * inv_n;
        float var = gsqs[c] * inv_n - mu * mu;
        float sc = rsqrtf(var + 1e-5f) * gamma[c];
        v[j] = (v[j] - mu) * sc + beta[c];
    }
    ((f32x4*)x)[i] = v;
}

// ---------------- launch ----------------

extern "C" void kernel_launch(void* const* d_in, const int* in_sizes, int n_in,
                              void* d_out, int out_size, void* d_ws, size_t ws_size,
                              hipStream_t stream) {
    const float* feat  = (const float*)d_in[0];
    const int*   src   = (const int*)d_in[1];
    const int*   dst   = (const int*)d_in[2];
    const float* W1    = (const float*)d_in[3];
    const float* b1    = (const float*)d_in[4];
    const float* W2    = (const float*)d_in[5];
    const float* b2    = (const float*)d_in[6];
    const float* W3    = (const float*)d_in[7];
    const float* b3    = (const float*)d_in[8];
    const float* gamma = (const float*)d_in[9];
    const float* beta  = (const float*)d_in[10];
    const float* mw1   = (const float*)d_in[11];
    const float* mb1   = (const float*)d_in[12];
    const float* mw2   = (const float*)d_in[13];
    const float* mb2   = (const float*)d_in[14];
    float* outp = (float*)d_out;

    const int n = in_sizes[0] / 128;
    const int e = in_sizes[1];

    char* w = (char*)d_ws;
    auto alloc = [&](size_t bytes) -> void* {
        void* p = (void*)w;
        w += (bytes + 255) & ~(size_t)255;
        return p;
    };
    float* buf0 = (float*)alloc((size_t)n * 128 * 4);
    float* buf1 = (float*)alloc((size_t)n * 128 * 4);
    float* buf2 = (float*)alloc((size_t)n * 128 * 4);
    float* buf3 = (float*)alloc((size_t)n * 128 * 4);
    int*   deg    = (int*)alloc((size_t)n * 4);
    float* dinv   = (float*)alloc((size_t)n * 4);
    int*   rowptr = (int*)alloc((size_t)(n + 1) * 4);
    int*   cursor = (int*)alloc((size_t)n * 4);
    int*   csrc   = (int*)alloc((size_t)e * 4);
    unsigned short* wp1  = (unsigned short*)alloc(12 * 8 * 512 * 2);
    unsigned short* wp2  = (unsigned short*)alloc(12 * 8 * 512 * 2);
    unsigned short* wp3  = (unsigned short*)alloc(12 * 8 * 512 * 2);
    unsigned short* wpm1 = (unsigned short*)alloc(4 * 8 * 512 * 2);
    unsigned short* wpm2 = (unsigned short*)alloc(4 * 4 * 512 * 2);
    float* gsum = (float*)alloc(128 * 4);
    float* gsqs = (float*)alloc(128 * 4);

    const int gE = (e + 255) / 256;
    const int gN = (n + 255) / 256;
    const int gGemm = (n + 63) / 64;
    const int gSpmm = (n + 3) / 4;
    const int gBnS = (n + 255) / 256;
    const int gBnA = (n * 32 + 255) / 256;

    // degree + CSR
    hipMemsetAsync(deg, 0, (size_t)n * 4, stream);
    deg_count_k<<<gE, 256, 0, stream>>>(dst, deg, e);
    dinv_k<<<gN, 256, 0, stream>>>(deg, dinv, n);
    scan_rowptr_k<<<1, 1024, 0, stream>>>(deg, rowptr, cursor, n);
    scatter_k<<<gE, 256, 0, stream>>>(src, dst, cursor, csrc, e);

    // weight packs
    pack_w_k<<<(12 * 8 * 64 + 255) / 256, 256, 0, stream>>>(W1, wp1, 384, 128, 1);
    pack_w_k<<<(12 * 8 * 64 + 255) / 256, 256, 0, stream>>>(W2, wp2, 384, 128, 1);
    pack_w_k<<<(12 * 8 * 64 + 255) / 256, 256, 0, stream>>>(W3, wp3, 384, 128, 1);
    pack_w_k<<<(4 * 8 * 64 + 255) / 256, 256, 0, stream>>>(mw1, wpm1, 128, 128, 0);
    pack_w_k<<<(4 * 4 * 64 + 255) / 256, 256, 0, stream>>>(mw2, wpm2, 128, 64, 0);

    // Layer 1: cheb(features, W1) -> relu -> buf0
    spmm_csr_k<<<gSpmm, 256, 0, stream>>>(feat, rowptr, csrc, dinv, buf1, n);
    spmm_csr_k<<<gSpmm, 256, 0, stream>>>(buf1, rowptr, csrc, dinv, buf2, n);
    gemm_k<12, 8, true, false><<<gGemm, 256, 0, stream>>>(feat, buf1, buf2, wp1, b1, nullptr, buf0, n);

    // BatchNorm on buf0 (in place)
    hipMemsetAsync(gsum, 0, 128 * 4, stream);
    hipMemsetAsync(gsqs, 0, 128 * 4, stream);
    bn_stats_k<<<gBnS, 256, 0, stream>>>(buf0, gsum, gsqs, n);
    bn_apply_k<<<gBnA, 256, 0, stream>>>(buf0, gsum, gsqs, gamma, beta, n, 1.0f / (float)n);

    // Layer 2a: cheb(buf0, W2) -> relu -> buf3
    spmm_csr_k<<<gSpmm, 256, 0, stream>>>(buf0, rowptr, csrc, dinv, buf1, n);
    spmm_csr_k<<<gSpmm, 256, 0, stream>>>(buf1, rowptr, csrc, dinv, buf2, n);
    gemm_k<12, 8, true, false><<<gGemm, 256, 0, stream>>>(buf0, buf1, buf2, wp2, b2, nullptr, buf3, n);

    // Layer 2b: cheb(buf3, W2) -> relu -> buf0
    spmm_csr_k<<<gSpmm, 256, 0, stream>>>(buf3, rowptr, csrc, dinv, buf1, n);
    spmm_csr_k<<<gSpmm, 256, 0, stream>>>(buf1, rowptr, csrc, dinv, buf2, n);
    gemm_k<12, 8, true, false><<<gGemm, 256, 0, stream>>>(buf3, buf1, buf2, wp2, b2, nullptr, buf0, n);

    // Layer 3: cheb(buf0, W3) -> relu -> + residual(buf0) -> buf3
    spmm_csr_k<<<gSpmm, 256, 0, stream>>>(buf0, rowptr, csrc, dinv, buf1, n);
    spmm_csr_k<<<gSpmm, 256, 0, stream>>>(buf1, rowptr, csrc, dinv, buf2, n);
    gemm_k<12, 8, true, true><<<gGemm, 256, 0, stream>>>(buf0, buf1, buf2, wp3, b3, buf0, buf3, n);

    // MLP: relu(buf3 @ mw1 + mb1) -> buf1 ; buf1 @ mw2 + mb2 -> out
    gemm_k<4, 8, true, false><<<gGemm, 256, 0, stream>>>(buf3, nullptr, nullptr, wpm1, mb1, nullptr, buf1, n);
    gemm_k<4, 4, false, false><<<gGemm, 256, 0, stream>>>(buf1, nullptr, nullptr, wpm2, mb2, nullptr, outp, n);
}

// Round 2
// 712.812 us; speedup vs baseline: 1.5321x; 1.5321x over previous
//
#include <hip/hip_runtime.h>
#include <hip/hip_bf16.h>

typedef __attribute__((ext_vector_type(4))) float f32x4;
typedef __attribute__((ext_vector_type(8))) short short8;

__device__ inline unsigned short f2bf(float f) {
    union { float f; unsigned int u; } v; v.f = f;
    unsigned int u = v.u;
    return (unsigned short)((u + 0x7fffu + ((u >> 16) & 1u)) >> 16);
}
__device__ inline float bf2f(unsigned short h) {
    union { unsigned int u; float f; } v; v.u = ((unsigned int)h) << 16; return v.f;
}
__device__ inline float bflo(unsigned int p) {
    union { unsigned int u; float f; } v; v.u = p << 16; return v.f;
}
__device__ inline float bfhi(unsigned int p) {
    union { unsigned int u; float f; } v; v.u = p & 0xffff0000u; return v.f;
}

// ---------------- fp32 -> bf16 cast ----------------

__global__ __launch_bounds__(256) void cast_k(const float* __restrict__ x, unsigned short* __restrict__ y, int n4) {
    int i = blockIdx.x * 256 + threadIdx.x;   // one f32x4 per thread
    if (i >= n4) return;
    f32x4 v = ((const f32x4*)x)[i];
    unsigned int lo = (unsigned int)f2bf(v[0]) | ((unsigned int)f2bf(v[1]) << 16);
    unsigned int hi = (unsigned int)f2bf(v[2]) | ((unsigned int)f2bf(v[3]) << 16);
    uint2 o; o.x = lo; o.y = hi;
    ((uint2*)y)[i] = o;
}

// ---------------- degree / CSR build (parallel scan) ----------------

__global__ __launch_bounds__(256) void deg_count_k(const int* __restrict__ dst, int* __restrict__ deg, int e) {
    int i = blockIdx.x * 256 + threadIdx.x;
    if (i < e) atomicAdd(&deg[dst[i]], 1);
}

// per-block (1024 elements) sums
__global__ __launch_bounds__(256) void partial_k(const int* __restrict__ deg, int* __restrict__ part, int n) {
    __shared__ int sm[256];
    int t = threadIdx.x;
    int base = blockIdx.x * 1024 + t * 4;
    int s = 0;
#pragma unroll
    for (int j = 0; j < 4; ++j) { int idx = base + j; if (idx < n) s += deg[idx]; }
    sm[t] = s;
    __syncthreads();
    for (int off = 128; off > 0; off >>= 1) {
        if (t < off) sm[t] += sm[t + off];
        __syncthreads();
    }
    if (t == 0) part[blockIdx.x] = sm[0];
}

// exclusive scan of block partials (nb <= 256)
__global__ __launch_bounds__(256) void scanpart_k(int* __restrict__ part, int nb) {
    __shared__ int sm[256];
    int t = threadIdx.x;
    int v = (t < nb) ? part[t] : 0;
    sm[t] = v;
    __syncthreads();
    for (int off = 1; off < 256; off <<= 1) {
        int u = (t >= off) ? sm[t - off] : 0;
        __syncthreads();
        sm[t] += u;
        __syncthreads();
    }
    if (t < nb) part[t] = sm[t] - v;   // exclusive
}

// local scan + write rowptr/cursor, fused dinv
__global__ __launch_bounds__(256) void rowptr_k(const int* __restrict__ deg, const int* __restrict__ part,
                                                int* __restrict__ rowptr, int* __restrict__ cursor,
                                                float* __restrict__ dinv, int n) {
    __shared__ int sm[256];
    int t = threadIdx.x;
    int base = blockIdx.x * 1024 + t * 4;
    int d[4]; int s = 0;
#pragma unroll
    for (int j = 0; j < 4; ++j) { int idx = base + j; d[j] = (idx < n) ? deg[idx] : 0; s += d[j]; }
    sm[t] = s;
    __syncthreads();
    for (int off = 1; off < 256; off <<= 1) {
        int u = (t >= off) ? sm[t - off] : 0;
        __syncthreads();
        sm[t] += u;
        __syncthreads();
    }
    int ex = part[blockIdx.x] + sm[t] - s;
#pragma unroll
    for (int j = 0; j < 4; ++j) {
        int idx = base + j;
        if (idx < n) {
            rowptr[idx] = ex; cursor[idx] = ex;
            dinv[idx] = rsqrtf(fmaxf((float)d[j], 1.0f));
        }
        ex += d[j];
    }
    if (blockIdx.x == gridDim.x - 1 && t == 255) rowptr[n] = part[blockIdx.x] + sm[255];
}

__global__ __launch_bounds__(256) void scatter_k(const int* __restrict__ src, const int* __restrict__ dst,
                                                 int* __restrict__ cursor, int* __restrict__ csrc, int e) {
    int i = blockIdx.x * 256 + threadIdx.x;
    if (i < e) {
        int p = atomicAdd(&cursor[dst[i]], 1);
        csrc[p] = src[i];
    }
}

__global__ __launch_bounds__(256) void wgt_k(const int* __restrict__ csrc, const float* __restrict__ dinv,
                                             float* __restrict__ wgt, int e) {
    int i = blockIdx.x * 256 + threadIdx.x;
    if (i < e) wgt[i] = dinv[csrc[i]];
}

// ---------------- SpMM (normalized adjacency), bf16 rows, CSR by dst ----------------
// out[d][:] = dinv[d] * sum_{s in in(d)} wgt * x[s][:]

__global__ __launch_bounds__(256) void spmm_bf_k(const unsigned short* __restrict__ x, const int* __restrict__ rowptr,
                                                 const int* __restrict__ csrc, const float* __restrict__ wgt,
                                                 const float* __restrict__ dinv,
                                                 unsigned short* __restrict__ out, int n) {
    int lane = threadIdx.x & 63;
    int wave = threadIdx.x >> 6;
    int node = blockIdx.x * 4 + wave;
    if (node >= n) return;
    int beg = rowptr[node], end = rowptr[node + 1];
    float a0 = 0.f, a1 = 0.f;
    int i = beg;
    for (; i + 2 <= end; i += 2) {
        int s0 = csrc[i], s1 = csrc[i + 1];
        float w0 = wgt[i], w1 = wgt[i + 1];
        unsigned int v0 = ((const unsigned int*)(x + (size_t)s0 * 128))[lane];
        unsigned int v1 = ((const unsigned int*)(x + (size_t)s1 * 128))[lane];
        a0 += w0 * bflo(v0) + w1 * bflo(v1);
        a1 += w0 * bfhi(v0) + w1 * bfhi(v1);
    }
    if (i < end) {
        int s0 = csrc[i]; float w0 = wgt[i];
        unsigned int v0 = ((const unsigned int*)(x + (size_t)s0 * 128))[lane];
        a0 += w0 * bflo(v0);
        a1 += w0 * bfhi(v0);
    }
    float dd = dinv[node];
    unsigned int o = (unsigned int)f2bf(a0 * dd) | ((unsigned int)f2bf(a1 * dd) << 16);
    ((unsigned int*)(out + (size_t)node * 128))[lane] = o;
}

// ---------------- weight pack into MFMA B-fragment order (bf16) ----------------
// wpack layout: [(ks*NF + f)*512 + lane*8 + j] = W'[ks*32 + (lane>>4)*8 + j][f*16 + (lane&15)]
// cheb mode: W' = [W0 - W2 ; -W1 ; 2*W2]  (K=384); else plain [K][N] row-major.

__global__ __launch_bounds__(256) void pack_w_k(const float* __restrict__ W, unsigned short* __restrict__ out,
                                                int K, int N, int cheb) {
    int id = blockIdx.x * 256 + threadIdx.x;
    int total = (K / 32) * (N / 16) * 64;
    if (id >= total) return;
    int lane = id & 63;
    int t2 = id >> 6;
    int nf = N / 16;
    int f = t2 % nf;
    int ks = t2 / nf;
    int col = f * 16 + (lane & 15);
    int kbase = ks * 32 + ((lane >> 4) * 8);
    for (int j = 0; j < 8; ++j) {
        int kg = kbase + j;
        float v;
        if (cheb) {
            int t = kg >> 7, kk = kg & 127;
            const float* W0 = W;
            const float* Wb = W + 16384;
            const float* Wc = W + 32768;
            float w0 = W0[kk * 128 + col], wb = Wb[kk * 128 + col], wc = Wc[kk * 128 + col];
            v = (t == 0) ? (w0 - wc) : (t == 1) ? (-wb) : (2.0f * wc);
        } else {
            v = W[(size_t)kg * N + col];
        }
        out[(size_t)id * 8 + j] = f2bf(v);
    }
}

// ---------------- MFMA GEMM: C[n x NF*16] = [s0|s1|s2](bf16) @ Wpack + bias ----------------

template<int KSTEPS, int NF, bool RELU, bool RES, bool OUTF32>
__global__ __launch_bounds__(256) void gemm_k(const unsigned short* __restrict__ s0,
                                              const unsigned short* __restrict__ s1,
                                              const unsigned short* __restrict__ s2,
                                              const unsigned short* __restrict__ wp,
                                              const float* __restrict__ bias,
                                              const unsigned short* __restrict__ resid,
                                              void* __restrict__ outv, int n) {
    int lane = threadIdx.x & 63;
    int wave = threadIdx.x >> 6;
    int row0 = blockIdx.x * 64 + wave * 16;
    if (row0 >= n) return;
    int rowA = row0 + (lane & 15);
    if (rowA >= n) rowA = n - 1;           // clamp reads; writes are guarded below
    int kg = (lane >> 4) * 8;

    f32x4 acc[NF];
#pragma unroll
    for (int f = 0; f < NF; ++f) acc[f] = (f32x4)(0.0f);

#pragma unroll
    for (int ks = 0; ks < KSTEPS; ++ks) {
        const unsigned short* sp;
        int kk;
        if (KSTEPS == 12) {
            sp = (ks < 4) ? s0 : ((ks < 8) ? s1 : s2);
            kk = (ks & 3) * 32 + kg;
        } else {
            sp = s0;
            kk = ks * 32 + kg;
        }
        short8 a = *(const short8*)(sp + (size_t)rowA * 128 + kk);
#pragma unroll
        for (int f = 0; f < NF; ++f) {
            short8 b = *(const short8*)(wp + ((size_t)(ks * NF + f) * 512 + lane * 8));
            acc[f] = __builtin_amdgcn_mfma_f32_16x16x32_bf16(a, b, acc[f], 0, 0, 0);
        }
    }

    int colb = lane & 15;
    int rowD = row0 + ((lane >> 4) << 2);
#pragma unroll
    for (int f = 0; f < NF; ++f) {
        int c = f * 16 + colb;
        float bv = bias[c];
#pragma unroll
        for (int r = 0; r < 4; ++r) {
            int row = rowD + r;
            if (row >= n) continue;
            float v = acc[f][r] + bv;
            if (RELU) v = fmaxf(v, 0.0f);
            if (RES) v += bf2f(resid[(size_t)row * 128 + c]);
            if (OUTF32) ((float*)outv)[(size_t)row * (NF * 16) + c] = v;
            else        ((unsigned short*)outv)[(size_t)row * (NF * 16) + c] = f2bf(v);
        }
    }
}

// ---------------- BatchNorm (training-mode batch stats) on bf16 buffer ----------------

__global__ __launch_bounds__(256) void bn_stats_k(const unsigned short* __restrict__ x, float* __restrict__ gsum,
                                                  float* __restrict__ gsqs, int n) {
    __shared__ float s1[256], s2[256];
    int c = threadIdx.x & 127;
    int h = threadIdx.x >> 7;
    int r0 = blockIdx.x * 256;
    int rend = r0 + 256; if (rend > n) rend = n;
    float a = 0.f, b = 0.f;
    for (int r = r0 + h; r < rend; r += 2) {
        float v = bf2f(x[(size_t)r * 128 + c]);
        a += v; b += v * v;
    }
    s1[threadIdx.x] = a; s2[threadIdx.x] = b;
    __syncthreads();
    if (threadIdx.x < 128) {
        a = s1[threadIdx.x] + s1[threadIdx.x + 128];
        b = s2[threadIdx.x] + s2[threadIdx.x + 128];
        atomicAdd(&gsum[c], a);
        atomicAdd(&gsqs[c], b);
    }
}

__global__ __launch_bounds__(256) void bn_apply_k(unsigned short* __restrict__ x, const float* __restrict__ gsum,
                                                  const float* __restrict__ gsqs, const float* __restrict__ gamma,
                                                  const float* __restrict__ beta, int n, float inv_n) {
    int i = blockIdx.x * 256 + threadIdx.x;   // over n*32 uint2 (4 bf16 each)
    if (i >= n * 32) return;
    int c4 = (i & 31) * 4;
    uint2 p = ((uint2*)x)[i];
    float f[4] = { bflo(p.x), bfhi(p.x), bflo(p.y), bfhi(p.y) };
#pragma unroll
    for (int j = 0; j < 4; ++j) {
        int c = c4 + j;
        float mu = gsum[c] * inv_n;
        float var = gsqs[c] * inv_n - mu * mu;
        float sc = rsqrtf(var + 1e-5f) * gamma[c];
        f[j] = (f[j] - mu) * sc + beta[c];
    }
    p.x = (unsigned int)f2bf(f[0]) | ((unsigned int)f2bf(f[1]) << 16);
    p.y = (unsigned int)f2bf(f[2]) | ((unsigned int)f2bf(f[3]) << 16);
    ((uint2*)x)[i] = p;
}

// ---------------- launch ----------------

extern "C" void kernel_launch(void* const* d_in, const int* in_sizes, int n_in,
                              void* d_out, int out_size, void* d_ws, size_t ws_size,
                              hipStream_t stream) {
    const float* feat  = (const float*)d_in[0];
    const int*   src   = (const int*)d_in[1];
    const int*   dst   = (const int*)d_in[2];
    const float* W1    = (const float*)d_in[3];
    const float* b1    = (const float*)d_in[4];
    const float* W2    = (const float*)d_in[5];
    const float* b2    = (const float*)d_in[6];
    const float* W3    = (const float*)d_in[7];
    const float* b3    = (const float*)d_in[8];
    const float* gamma = (const float*)d_in[9];
    const float* beta  = (const float*)d_in[10];
    const float* mw1   = (const float*)d_in[11];
    const float* mb1   = (const float*)d_in[12];
    const float* mw2   = (const float*)d_in[13];
    const float* mb2   = (const float*)d_in[14];
    float* outp = (float*)d_out;

    const int n = in_sizes[0] / 128;
    const int e = in_sizes[1];

    char* w = (char*)d_ws;
    auto alloc = [&](size_t bytes) -> void* {
        void* p = (void*)w;
        w += (bytes + 255) & ~(size_t)255;
        return p;
    };
    unsigned short* featb = (unsigned short*)alloc((size_t)n * 128 * 2);
    unsigned short* buf0  = (unsigned short*)alloc((size_t)n * 128 * 2);
    unsigned short* buf1  = (unsigned short*)alloc((size_t)n * 128 * 2);
    unsigned short* buf2  = (unsigned short*)alloc((size_t)n * 128 * 2);
    unsigned short* buf3  = (unsigned short*)alloc((size_t)n * 128 * 2);
    int*   deg    = (int*)alloc((size_t)n * 4);
    float* dinv   = (float*)alloc((size_t)n * 4);
    int*   rowptr = (int*)alloc((size_t)(n + 1) * 4);
    int*   cursor = (int*)alloc((size_t)n * 4);
    int*   csrc   = (int*)alloc((size_t)e * 4);
    float* wgt    = (float*)alloc((size_t)e * 4);
    int*   part   = (int*)alloc(256 * 4);
    unsigned short* wp1  = (unsigned short*)alloc(12 * 8 * 512 * 2);
    unsigned short* wp2  = (unsigned short*)alloc(12 * 8 * 512 * 2);
    unsigned short* wp3  = (unsigned short*)alloc(12 * 8 * 512 * 2);
    unsigned short* wpm1 = (unsigned short*)alloc(4 * 8 * 512 * 2);
    unsigned short* wpm2 = (unsigned short*)alloc(4 * 4 * 512 * 2);
    float* gsum = (float*)alloc(128 * 4);
    float* gsqs = (float*)alloc(128 * 4);

    const int gE = (e + 255) / 256;
    const int gGemm = (n + 63) / 64;
    const int gSpmm = (n + 3) / 4;
    const int gBnS = (n + 255) / 256;
    const int gBnA = (n * 32 + 255) / 256;
    const int nb = (n + 1023) / 1024;

    // feat -> bf16
    cast_k<<<(n * 32 + 255) / 256, 256, 0, stream>>>(feat, featb, n * 32);

    // degree + CSR (parallel scan) + dinv + per-edge weights
    hipMemsetAsync(deg, 0, (size_t)n * 4, stream);
    deg_count_k<<<gE, 256, 0, stream>>>(dst, deg, e);
    partial_k<<<nb, 256, 0, stream>>>(deg, part, n);
    scanpart_k<<<1, 256, 0, stream>>>(part, nb);
    rowptr_k<<<nb, 256, 0, stream>>>(deg, part, rowptr, cursor, dinv, n);
    scatter_k<<<gE, 256, 0, stream>>>(src, dst, cursor, csrc, e);
    wgt_k<<<gE, 256, 0, stream>>>(csrc, dinv, wgt, e);

    // weight packs
    pack_w_k<<<(12 * 8 * 64 + 255) / 256, 256, 0, stream>>>(W1, wp1, 384, 128, 1);
    pack_w_k<<<(12 * 8 * 64 + 255) / 256, 256, 0, stream>>>(W2, wp2, 384, 128, 1);
    pack_w_k<<<(12 * 8 * 64 + 255) / 256, 256, 0, stream>>>(W3, wp3, 384, 128, 1);
    pack_w_k<<<(4 * 8 * 64 + 255) / 256, 256, 0, stream>>>(mw1, wpm1, 128, 128, 0);
    pack_w_k<<<(4 * 4 * 64 + 255) / 256, 256, 0, stream>>>(mw2, wpm2, 128, 64, 0);

    // Layer 1: cheb(features, W1) -> relu -> buf0
    spmm_bf_k<<<gSpmm, 256, 0, stream>>>(featb, rowptr, csrc, wgt, dinv, buf1, n);
    spmm_bf_k<<<gSpmm, 256, 0, stream>>>(buf1, rowptr, csrc, wgt, dinv, buf2, n);
    gemm_k<12, 8, true, false, false><<<gGemm, 256, 0, stream>>>(featb, buf1, buf2, wp1, b1, nullptr, buf0, n);

    // BatchNorm on buf0 (in place)
    hipMemsetAsync(gsum, 0, 128 * 4, stream);
    hipMemsetAsync(gsqs, 0, 128 * 4, stream);
    bn_stats_k<<<gBnS, 256, 0, stream>>>(buf0, gsum, gsqs, n);
    bn_apply_k<<<gBnA, 256, 0, stream>>>(buf0, gsum, gsqs, gamma, beta, n, 1.0f / (float)n);

    // Layer 2a: cheb(buf0, W2) -> relu -> buf3
    spmm_bf_k<<<gSpmm, 256, 0, stream>>>(buf0, rowptr, csrc, wgt, dinv, buf1, n);
    spmm_bf_k<<<gSpmm, 256, 0, stream>>>(buf1, rowptr, csrc, wgt, dinv, buf2, n);
    gemm_k<12, 8, true, false, false><<<gGemm, 256, 0, stream>>>(buf0, buf1, buf2, wp2, b2, nullptr, buf3, n);

    // Layer 2b: cheb(buf3, W2) -> relu -> buf0
    spmm_bf_k<<<gSpmm, 256, 0, stream>>>(buf3, rowptr, csrc, wgt, dinv, buf1, n);
    spmm_bf_k<<<gSpmm, 256, 0, stream>>>(buf1, rowptr, csrc, wgt, dinv, buf2, n);
    gemm_k<12, 8, true, false, false><<<gGemm, 256, 0, stream>>>(buf3, buf1, buf2, wp2, b2, nullptr, buf0, n);

    // Layer 3: cheb(buf0, W3) -> relu -> + residual(buf0) -> buf3
    spmm_bf_k<<<gSpmm, 256, 0, stream>>>(buf0, rowptr, csrc, wgt, dinv, buf1, n);
    spmm_bf_k<<<gSpmm, 256, 0, stream>>>(buf1, rowptr, csrc, wgt, dinv, buf2, n);
    gemm_k<12, 8, true, true, false><<<gGemm, 256, 0, stream>>>(buf0, buf1, buf2, wp3, b3, buf0, buf3, n);

    // MLP: relu(buf3 @ mw1 + mb1) -> buf1 ; buf1 @ mw2 + mb2 -> out (fp32)
    gemm_k<4, 8, true, false, false><<<gGemm, 256, 0, stream>>>(buf3, nullptr, nullptr, wpm1, mb1, nullptr, buf1, n);
    gemm_k<4, 4, false, false, true><<<gGemm, 256, 0, stream>>>(buf1, nullptr, nullptr, wpm2, mb2, nullptr, outp, n);
}

// Round 3
// 575.738 us; speedup vs baseline: 1.8968x; 1.2381x over previous
//
#include <hip/hip_runtime.h>
#include <hip/hip_bf16.h>

typedef __attribute__((ext_vector_type(4))) float f32x4;
typedef __attribute__((ext_vector_type(8))) short short8;

__device__ inline unsigned short f2bf(float f) {
    union { float f; unsigned int u; } v; v.f = f;
    unsigned int u = v.u;
    return (unsigned short)((u + 0x7fffu + ((u >> 16) & 1u)) >> 16);
}
__device__ inline float bf2f(unsigned short h) {
    union { unsigned int u; float f; } v; v.u = ((unsigned int)h) << 16; return v.f;
}
__device__ inline float bflo(unsigned int p) {
    union { unsigned int u; float f; } v; v.u = p << 16; return v.f;
}
__device__ inline float bfhi(unsigned int p) {
    union { unsigned int u; float f; } v; v.u = p & 0xffff0000u; return v.f;
}

// ---------------- fp32 -> bf16 cast ----------------

__global__ __launch_bounds__(256) void cast_k(const float* __restrict__ x, unsigned short* __restrict__ y, int n4) {
    int i = blockIdx.x * 256 + threadIdx.x;   // one f32x4 per thread
    if (i >= n4) return;
    f32x4 v = ((const f32x4*)x)[i];
    unsigned int lo = (unsigned int)f2bf(v[0]) | ((unsigned int)f2bf(v[1]) << 16);
    unsigned int hi = (unsigned int)f2bf(v[2]) | ((unsigned int)f2bf(v[3]) << 16);
    uint2 o; o.x = lo; o.y = hi;
    ((uint2*)y)[i] = o;
}

// ---------------- degree / CSR build (parallel scan) ----------------

__global__ __launch_bounds__(256) void deg_count_k(const int* __restrict__ dst, int* __restrict__ deg, int e) {
    int i = blockIdx.x * 256 + threadIdx.x;
    if (i < e) atomicAdd(&deg[dst[i]], 1);
}

// per-block (1024 elements) sums
__global__ __launch_bounds__(256) void partial_k(const int* __restrict__ deg, int* __restrict__ part, int n) {
    __shared__ int sm[256];
    int t = threadIdx.x;
    int base = blockIdx.x * 1024 + t * 4;
    int s = 0;
#pragma unroll
    for (int j = 0; j < 4; ++j) { int idx = base + j; if (idx < n) s += deg[idx]; }
    sm[t] = s;
    __syncthreads();
    for (int off = 128; off > 0; off >>= 1) {
        if (t < off) sm[t] += sm[t + off];
        __syncthreads();
    }
    if (t == 0) part[blockIdx.x] = sm[0];
}

// exclusive scan of block partials (nb <= 256)
__global__ __launch_bounds__(256) void scanpart_k(int* __restrict__ part, int nb) {
    __shared__ int sm[256];
    int t = threadIdx.x;
    int v = (t < nb) ? part[t] : 0;
    sm[t] = v;
    __syncthreads();
    for (int off = 1; off < 256; off <<= 1) {
        int u = (t >= off) ? sm[t - off] : 0;
        __syncthreads();
        sm[t] += u;
        __syncthreads();
    }
    if (t < nb) part[t] = sm[t] - v;   // exclusive
}

// local scan + write rowptr/cursor, fused dinv
__global__ __launch_bounds__(256) void rowptr_k(const int* __restrict__ deg, const int* __restrict__ part,
                                                int* __restrict__ rowptr, int* __restrict__ cursor,
                                                float* __restrict__ dinv, int n) {
    __shared__ int sm[256];
    int t = threadIdx.x;
    int base = blockIdx.x * 1024 + t * 4;
    int d[4]; int s = 0;
#pragma unroll
    for (int j = 0; j < 4; ++j) { int idx = base + j; d[j] = (idx < n) ? deg[idx] : 0; s += d[j]; }
    sm[t] = s;
    __syncthreads();
    for (int off = 1; off < 256; off <<= 1) {
        int u = (t >= off) ? sm[t - off] : 0;
        __syncthreads();
        sm[t] += u;
        __syncthreads();
    }
    int ex = part[blockIdx.x] + sm[t] - s;
#pragma unroll
    for (int j = 0; j < 4; ++j) {
        int idx = base + j;
        if (idx < n) {
            rowptr[idx] = ex; cursor[idx] = ex;
            dinv[idx] = rsqrtf(fmaxf((float)d[j], 1.0f));
        }
        ex += d[j];
    }
    if (blockIdx.x == gridDim.x - 1 && t == 255) rowptr[n] = part[blockIdx.x] + sm[255];
}

// scatter edges into CSR; fused per-edge weight = dinv[src]
__global__ __launch_bounds__(256) void scatter_k(const int* __restrict__ src, const int* __restrict__ dst,
                                                 int* __restrict__ cursor, int* __restrict__ csrc,
                                                 const float* __restrict__ dinv, float* __restrict__ wgt, int e) {
    int i = blockIdx.x * 256 + threadIdx.x;
    if (i < e) {
        int s = src[i];
        int p = atomicAdd(&cursor[dst[i]], 1);
        csrc[p] = s;
        wgt[p] = dinv[s];
    }
}

// ---------------- SpMM (normalized adjacency), bf16 rows, CSR by dst ----------------
// out[d][:] = dinv[d] * sum_{s in in(d)} wgt * x[s][:]
// unroll 4: indices/weights first, then 4 independent row gathers in flight.

__global__ __launch_bounds__(256) void spmm_bf_k(const unsigned short* __restrict__ x, const int* __restrict__ rowptr,
                                                 const int* __restrict__ csrc, const float* __restrict__ wgt,
                                                 const float* __restrict__ dinv,
                                                 unsigned short* __restrict__ out, int n) {
    int lane = threadIdx.x & 63;
    int wave = threadIdx.x >> 6;
    int node = blockIdx.x * 4 + wave;
    if (node >= n) return;
    int beg = rowptr[node], end = rowptr[node + 1];
    float a0 = 0.f, a1 = 0.f;
    int i = beg;
    for (; i + 4 <= end; i += 4) {
        int s0 = csrc[i], s1 = csrc[i + 1], s2 = csrc[i + 2], s3 = csrc[i + 3];
        float w0 = wgt[i], w1 = wgt[i + 1], w2 = wgt[i + 2], w3 = wgt[i + 3];
        unsigned int v0 = ((const unsigned int*)(x + (size_t)s0 * 128))[lane];
        unsigned int v1 = ((const unsigned int*)(x + (size_t)s1 * 128))[lane];
        unsigned int v2 = ((const unsigned int*)(x + (size_t)s2 * 128))[lane];
        unsigned int v3 = ((const unsigned int*)(x + (size_t)s3 * 128))[lane];
        a0 += w0 * bflo(v0) + w1 * bflo(v1) + w2 * bflo(v2) + w3 * bflo(v3);
        a1 += w0 * bfhi(v0) + w1 * bfhi(v1) + w2 * bfhi(v2) + w3 * bfhi(v3);
    }
    if (i + 2 <= end) {
        int s0 = csrc[i], s1 = csrc[i + 1];
        float w0 = wgt[i], w1 = wgt[i + 1];
        unsigned int v0 = ((const unsigned int*)(x + (size_t)s0 * 128))[lane];
        unsigned int v1 = ((const unsigned int*)(x + (size_t)s1 * 128))[lane];
        a0 += w0 * bflo(v0) + w1 * bflo(v1);
        a1 += w0 * bfhi(v0) + w1 * bfhi(v1);
        i += 2;
    }
    if (i < end) {
        int s0 = csrc[i]; float w0 = wgt[i];
        unsigned int v0 = ((const unsigned int*)(x + (size_t)s0 * 128))[lane];
        a0 += w0 * bflo(v0);
        a1 += w0 * bfhi(v0);
    }
    float dd = dinv[node];
    unsigned int o = (unsigned int)f2bf(a0 * dd) | ((unsigned int)f2bf(a1 * dd) << 16);
    ((unsigned int*)(out + (size_t)node * 128))[lane] = o;
}

// ---------------- weight pack into MFMA B-fragment order (bf16) ----------------
// wpack layout: [(ks*NF + f)*512 + lane*8 + j] = W'[ks*32 + (lane>>4)*8 + j][f*16 + (lane&15)]
// cheb mode: W' = [W0 - W2 ; -W1 ; 2*W2]  (K=384); else plain [K][N] row-major.

__global__ __launch_bounds__(256) void pack_w_k(const float* __restrict__ W, unsigned short* __restrict__ out,
                                                int K, int N, int cheb) {
    int id = blockIdx.x * 256 + threadIdx.x;
    int total = (K / 32) * (N / 16) * 64;
    if (id >= total) return;
    int lane = id & 63;
    int t2 = id >> 6;
    int nf = N / 16;
    int f = t2 % nf;
    int ks = t2 / nf;
    int col = f * 16 + (lane & 15);
    int kbase = ks * 32 + ((lane >> 4) * 8);
    for (int j = 0; j < 8; ++j) {
        int kg = kbase + j;
        float v;
        if (cheb) {
            int t = kg >> 7, kk = kg & 127;
            const float* W0 = W;
            const float* Wb = W + 16384;
            const float* Wc = W + 32768;
            float w0 = W0[kk * 128 + col], wb = Wb[kk * 128 + col], wc = Wc[kk * 128 + col];
            v = (t == 0) ? (w0 - wc) : (t == 1) ? (-wb) : (2.0f * wc);
        } else {
            v = W[(size_t)kg * N + col];
        }
        out[(size_t)id * 8 + j] = f2bf(v);
    }
}

// ---------------- MFMA GEMM: C[n x NF*16] = [s0|s1|s2](bf16) @ Wpack + bias ----------------

template<int KSTEPS, int NF, bool RELU, bool RES, bool OUTF32>
__global__ __launch_bounds__(256) void gemm_k(const unsigned short* __restrict__ s0,
                                              const unsigned short* __restrict__ s1,
                                              const unsigned short* __restrict__ s2,
                                              const unsigned short* __restrict__ wp,
                                              const float* __restrict__ bias,
                                              const unsigned short* __restrict__ resid,
                                              void* __restrict__ outv, int n) {
    int lane = threadIdx.x & 63;
    int wave = threadIdx.x >> 6;
    int row0 = blockIdx.x * 64 + wave * 16;
    if (row0 >= n) return;
    int rowA = row0 + (lane & 15);
    if (rowA >= n) rowA = n - 1;           // clamp reads; writes are guarded below
    int kg = (lane >> 4) * 8;

    f32x4 acc[NF];
#pragma unroll
    for (int f = 0; f < NF; ++f) acc[f] = (f32x4)(0.0f);

#pragma unroll
    for (int ks = 0; ks < KSTEPS; ++ks) {
        const unsigned short* sp;
        int kk;
        if (KSTEPS == 12) {
            sp = (ks < 4) ? s0 : ((ks < 8) ? s1 : s2);
            kk = (ks & 3) * 32 + kg;
        } else {
            sp = s0;
            kk = ks * 32 + kg;
        }
        short8 a = *(const short8*)(sp + (size_t)rowA * 128 + kk);
#pragma unroll
        for (int f = 0; f < NF; ++f) {
            short8 b = *(const short8*)(wp + ((size_t)(ks * NF + f) * 512 + lane * 8));
            acc[f] = __builtin_amdgcn_mfma_f32_16x16x32_bf16(a, b, acc[f], 0, 0, 0);
        }
    }

    int colb = lane & 15;
    int rowD = row0 + ((lane >> 4) << 2);
#pragma unroll
    for (int f = 0; f < NF; ++f) {
        int c = f * 16 + colb;
        float bv = bias[c];
#pragma unroll
        for (int r = 0; r < 4; ++r) {
            int row = rowD + r;
            if (row >= n) continue;
            float v = acc[f][r] + bv;
            if (RELU) v = fmaxf(v, 0.0f);
            if (RES) v += bf2f(resid[(size_t)row * 128 + c]);
            if (OUTF32) ((float*)outv)[(size_t)row * (NF * 16) + c] = v;
            else        ((unsigned short*)outv)[(size_t)row * (NF * 16) + c] = f2bf(v);
        }
    }
}

// ---------------- fused MLP: out = relu(x@mw1+mb1)@mw2 + mb2 ----------------
// Stage t = relu(x@mw1+mb1) (64x128 bf16) in XOR-swizzled LDS, then GEMM2 from LDS.

__global__ __launch_bounds__(256) void mlp_fused_k(const unsigned short* __restrict__ x,
                                                   const unsigned short* __restrict__ wp1,
                                                   const float* __restrict__ mb1,
                                                   const unsigned short* __restrict__ wp2,
                                                   const float* __restrict__ mb2,
                                                   float* __restrict__ out, int n) {
    __shared__ unsigned short tlds[64 * 128];   // 16 KiB
    int lane = threadIdx.x & 63;
    int wave = threadIdx.x >> 6;
    int row0 = blockIdx.x * 64 + wave * 16;
    int rowA = row0 + (lane & 15);
    if (rowA >= n) rowA = n - 1;
    int kg = (lane >> 4) * 8;
    int colb = lane & 15;

    // GEMM1: t = relu(x@mw1 + mb1)
    f32x4 acc[8];
#pragma unroll
    for (int f = 0; f < 8; ++f) acc[f] = (f32x4)(0.0f);
#pragma unroll
    for (int ks = 0; ks < 4; ++ks) {
        short8 a = *(const short8*)(x + (size_t)rowA * 128 + ks * 32 + kg);
#pragma unroll
        for (int f = 0; f < 8; ++f) {
            short8 b = *(const short8*)(wp1 + ((size_t)(ks * 8 + f) * 512 + lane * 8));
            acc[f] = __builtin_amdgcn_mfma_f32_16x16x32_bf16(a, b, acc[f], 0, 0, 0);
        }
    }
    int lrowD = wave * 16 + ((lane >> 4) << 2);
#pragma unroll
    for (int f = 0; f < 8; ++f) {
        int c = f * 16 + colb;
        float bv = mb1[c];
#pragma unroll
        for (int r = 0; r < 4; ++r) {
            int lrow = lrowD + r;
            float v = fmaxf(acc[f][r] + bv, 0.0f);
            int byte = lrow * 256 + c * 2;
            byte ^= ((lrow & 7) << 4);
            *(unsigned short*)((char*)tlds + byte) = f2bf(v);
        }
    }
    __syncthreads();

    // GEMM2: out = t@mw2 + mb2 (N=64)
    f32x4 acc2[4];
#pragma unroll
    for (int f = 0; f < 4; ++f) acc2[f] = (f32x4)(0.0f);
    int lrowA = wave * 16 + (lane & 15);
#pragma unroll
    for (int ks = 0; ks < 4; ++ks) {
        int byte = lrowA * 256 + (ks * 32 + kg) * 2;
        byte ^= ((lrowA & 7) << 4);
        short8 a = *(const short8*)((const char*)tlds + byte);
#pragma unroll
        for (int f = 0; f < 4; ++f) {
            short8 b = *(const short8*)(wp2 + ((size_t)(ks * 4 + f) * 512 + lane * 8));
            acc2[f] = __builtin_amdgcn_mfma_f32_16x16x32_bf16(a, b, acc2[f], 0, 0, 0);
        }
    }
    int rowD = row0 + ((lane >> 4) << 2);
#pragma unroll
    for (int f = 0; f < 4; ++f) {
        int c = f * 16 + colb;
        float bv = mb2[c];
#pragma unroll
        for (int r = 0; r < 4; ++r) {
            int row = rowD + r;
            if (row >= n) continue;
            out[(size_t)row * 64 + c] = acc2[f][r] + bv;
        }
    }
}

// ---------------- BatchNorm (training-mode batch stats) on bf16 buffer ----------------

__global__ __launch_bounds__(256) void bn_stats_k(const unsigned short* __restrict__ x, float* __restrict__ gsum,
                                                  float* __restrict__ gsqs, int n) {
    __shared__ float s1[256], s2[256];
    int c = threadIdx.x & 127;
    int h = threadIdx.x >> 7;
    int r0 = blockIdx.x * 256;
    int rend = r0 + 256; if (rend > n) rend = n;
    float a = 0.f, b = 0.f;
    for (int r = r0 + h; r < rend; r += 2) {
        float v = bf2f(x[(size_t)r * 128 + c]);
        a += v; b += v * v;
    }
    s1[threadIdx.x] = a; s2[threadIdx.x] = b;
    __syncthreads();
    if (threadIdx.x < 128) {
        a = s1[threadIdx.x] + s1[threadIdx.x + 128];
        b = s2[threadIdx.x] + s2[threadIdx.x + 128];
        atomicAdd(&gsum[c], a);
        atomicAdd(&gsqs[c], b);
    }
}

__global__ __launch_bounds__(256) void bn_apply_k(unsigned short* __restrict__ x, const float* __restrict__ gsum,
                                                  const float* __restrict__ gsqs, const float* __restrict__ gamma,
                                                  const float* __restrict__ beta, int n, float inv_n) {
    int i = blockIdx.x * 256 + threadIdx.x;   // over n*32 uint2 (4 bf16 each)
    if (i >= n * 32) return;
    int c4 = (i & 31) * 4;
    uint2 p = ((uint2*)x)[i];
    float f[4] = { bflo(p.x), bfhi(p.x), bflo(p.y), bfhi(p.y) };
#pragma unroll
    for (int j = 0; j < 4; ++j) {
        int c = c4 + j;
        float mu = gsum[c] * inv_n;
        float var = gsqs[c] * inv_n - mu * mu;
        float sc = rsqrtf(var + 1e-5f) * gamma[c];
        f[j] = (f[j] - mu) * sc + beta[c];
    }
    p.x = (unsigned int)f2bf(f[0]) | ((unsigned int)f2bf(f[1]) << 16);
    p.y = (unsigned int)f2bf(f[2]) | ((unsigned int)f2bf(f[3]) << 16);
    ((uint2*)x)[i] = p;
}

// ---------------- launch ----------------

extern "C" void kernel_launch(void* const* d_in, const int* in_sizes, int n_in,
                              void* d_out, int out_size, void* d_ws, size_t ws_size,
                              hipStream_t stream) {
    const float* feat  = (const float*)d_in[0];
    const int*   src   = (const int*)d_in[1];
    const int*   dst   = (const int*)d_in[2];
    const float* W1    = (const float*)d_in[3];
    const float* b1    = (const float*)d_in[4];
    const float* W2    = (const float*)d_in[5];
    const float* b2    = (const float*)d_in[6];
    const float* W3    = (const float*)d_in[7];
    const float* b3    = (const float*)d_in[8];
    const float* gamma = (const float*)d_in[9];
    const float* beta  = (const float*)d_in[10];
    const float* mw1   = (const float*)d_in[11];
    const float* mb1   = (const float*)d_in[12];
    const float* mw2   = (const float*)d_in[13];
    const float* mb2   = (const float*)d_in[14];
    float* outp = (float*)d_out;

    const int n = in_sizes[0] / 128;
    const int e = in_sizes[1];

    char* w = (char*)d_ws;
    auto alloc = [&](size_t bytes) -> void* {
        void* p = (void*)w;
        w += (bytes + 255) & ~(size_t)255;
        return p;
    };
    unsigned short* featb = (unsigned short*)alloc((size_t)n * 128 * 2);
    unsigned short* buf0  = (unsigned short*)alloc((size_t)n * 128 * 2);
    unsigned short* buf1  = (unsigned short*)alloc((size_t)n * 128 * 2);
    unsigned short* buf2  = (unsigned short*)alloc((size_t)n * 128 * 2);
    unsigned short* buf3  = (unsigned short*)alloc((size_t)n * 128 * 2);
    int*   deg    = (int*)alloc((size_t)n * 4);
    float* dinv   = (float*)alloc((size_t)n * 4);
    int*   rowptr = (int*)alloc((size_t)(n + 1) * 4);
    int*   cursor = (int*)alloc((size_t)n * 4);
    int*   csrc   = (int*)alloc((size_t)e * 4);
    float* wgt    = (float*)alloc((size_t)e * 4);
    int*   part   = (int*)alloc(256 * 4);
    unsigned short* wp1  = (unsigned short*)alloc(12 * 8 * 512 * 2);
    unsigned short* wp2  = (unsigned short*)alloc(12 * 8 * 512 * 2);
    unsigned short* wp3  = (unsigned short*)alloc(12 * 8 * 512 * 2);
    unsigned short* wpm1 = (unsigned short*)alloc(4 * 8 * 512 * 2);
    unsigned short* wpm2 = (unsigned short*)alloc(4 * 4 * 512 * 2);
    float* gsum = (float*)alloc(128 * 4);
    float* gsqs = (float*)alloc(128 * 4);

    const int gE = (e + 255) / 256;
    const int gGemm = (n + 63) / 64;
    const int gSpmm = (n + 3) / 4;
    const int gBnS = (n + 255) / 256;
    const int gBnA = (n * 32 + 255) / 256;
    const int nb = (n + 1023) / 1024;

    // feat -> bf16
    cast_k<<<(n * 32 + 255) / 256, 256, 0, stream>>>(feat, featb, n * 32);

    // degree + CSR (parallel scan) + dinv + per-edge weights
    hipMemsetAsync(deg, 0, (size_t)n * 4, stream);
    deg_count_k<<<gE, 256, 0, stream>>>(dst, deg, e);
    partial_k<<<nb, 256, 0, stream>>>(deg, part, n);
    scanpart_k<<<1, 256, 0, stream>>>(part, nb);
    rowptr_k<<<nb, 256, 0, stream>>>(deg, part, rowptr, cursor, dinv, n);
    scatter_k<<<gE, 256, 0, stream>>>(src, dst, cursor, csrc, dinv, wgt, e);

    // weight packs
    pack_w_k<<<(12 * 8 * 64 + 255) / 256, 256, 0, stream>>>(W1, wp1, 384, 128, 1);
    pack_w_k<<<(12 * 8 * 64 + 255) / 256, 256, 0, stream>>>(W2, wp2, 384, 128, 1);
    pack_w_k<<<(12 * 8 * 64 + 255) / 256, 256, 0, stream>>>(W3, wp3, 384, 128, 1);
    pack_w_k<<<(4 * 8 * 64 + 255) / 256, 256, 0, stream>>>(mw1, wpm1, 128, 128, 0);
    pack_w_k<<<(4 * 4 * 64 + 255) / 256, 256, 0, stream>>>(mw2, wpm2, 128, 64, 0);

    // Layer 1: cheb(features, W1) -> relu -> buf0
    spmm_bf_k<<<gSpmm, 256, 0, stream>>>(featb, rowptr, csrc, wgt, dinv, buf1, n);
    spmm_bf_k<<<gSpmm, 256, 0, stream>>>(buf1, rowptr, csrc, wgt, dinv, buf2, n);
    gemm_k<12, 8, true, false, false><<<gGemm, 256, 0, stream>>>(featb, buf1, buf2, wp1, b1, nullptr, buf0, n);

    // BatchNorm on buf0 (in place)
    hipMemsetAsync(gsum, 0, 128 * 4, stream);
    hipMemsetAsync(gsqs, 0, 128 * 4, stream);
    bn_stats_k<<<gBnS, 256, 0, stream>>>(buf0, gsum, gsqs, n);
    bn_apply_k<<<gBnA, 256, 0, stream>>>(buf0, gsum, gsqs, gamma, beta, n, 1.0f / (float)n);

    // Layer 2a: cheb(buf0, W2) -> relu -> buf3
    spmm_bf_k<<<gSpmm, 256, 0, stream>>>(buf0, rowptr, csrc, wgt, dinv, buf1, n);
    spmm_bf_k<<<gSpmm, 256, 0, stream>>>(buf1, rowptr, csrc, wgt, dinv, buf2, n);
    gemm_k<12, 8, true, false, false><<<gGemm, 256, 0, stream>>>(buf0, buf1, buf2, wp2, b2, nullptr, buf3, n);

    // Layer 2b: cheb(buf3, W2) -> relu -> buf0
    spmm_bf_k<<<gSpmm, 256, 0, stream>>>(buf3, rowptr, csrc, wgt, dinv, buf1, n);
    spmm_bf_k<<<gSpmm, 256, 0, stream>>>(buf1, rowptr, csrc, wgt, dinv, buf2, n);
    gemm_k<12, 8, true, false, false><<<gGemm, 256, 0, stream>>>(buf3, buf1, buf2, wp2, b2, nullptr, buf0, n);

    // Layer 3: cheb(buf0, W3) -> relu -> + residual(buf0) -> buf3
    spmm_bf_k<<<gSpmm, 256, 0, stream>>>(buf0, rowptr, csrc, wgt, dinv, buf1, n);
    spmm_bf_k<<<gSpmm, 256, 0, stream>>>(buf1, rowptr, csrc, wgt, dinv, buf2, n);
    gemm_k<12, 8, true, true, false><<<gGemm, 256, 0, stream>>>(buf0, buf1, buf2, wp3, b3, buf0, buf3, n);

    // fused MLP: out = relu(buf3@mw1+mb1)@mw2 + mb2 (fp32 out)
    mlp_fused_k<<<gGemm, 256, 0, stream>>>(buf3, wpm1, mb1, wpm2, mb2, outp, n);
}

// Round 4
// 559.730 us; speedup vs baseline: 1.9511x; 1.0286x over previous
//
#include <hip/hip_runtime.h>
#include <hip/hip_bf16.h>

typedef __attribute__((ext_vector_type(4))) float f32x4;
typedef __attribute__((ext_vector_type(8))) short short8;

__device__ inline unsigned short f2bf(float f) {
    union { float f; unsigned int u; } v; v.f = f;
    unsigned int u = v.u;
    return (unsigned short)((u + 0x7fffu + ((u >> 16) & 1u)) >> 16);
}
__device__ inline float bf2f(unsigned short h) {
    union { unsigned int u; float f; } v; v.u = ((unsigned int)h) << 16; return v.f;
}
__device__ inline float bflo(unsigned int p) {
    union { unsigned int u; float f; } v; v.u = p << 16; return v.f;
}
__device__ inline float bfhi(unsigned int p) {
    union { unsigned int u; float f; } v; v.u = p & 0xffff0000u; return v.f;
}
__device__ inline unsigned int packbf(float a, float b) {
    return (unsigned int)f2bf(a) | ((unsigned int)f2bf(b) << 16);
}

// ---------------- fp32 -> bf16 cast ----------------

__global__ __launch_bounds__(256) void cast_k(const float* __restrict__ x, unsigned short* __restrict__ y, int n4) {
    int i = blockIdx.x * 256 + threadIdx.x;   // one f32x4 per thread
    if (i >= n4) return;
    f32x4 v = ((const f32x4*)x)[i];
    uint2 o; o.x = packbf(v[0], v[1]); o.y = packbf(v[2], v[3]);
    ((uint2*)y)[i] = o;
}

// ---------------- degree / CSR build (parallel scan) ----------------

__global__ __launch_bounds__(256) void deg_count_k(const int* __restrict__ dst, int* __restrict__ deg, int e) {
    int i = blockIdx.x * 256 + threadIdx.x;
    if (i < e) atomicAdd(&deg[dst[i]], 1);
}

// per-block (1024 elements) sums
__global__ __launch_bounds__(256) void partial_k(const int* __restrict__ deg, int* __restrict__ part, int n) {
    __shared__ int sm[256];
    int t = threadIdx.x;
    int base = blockIdx.x * 1024 + t * 4;
    int s = 0;
#pragma unroll
    for (int j = 0; j < 4; ++j) { int idx = base + j; if (idx < n) s += deg[idx]; }
    sm[t] = s;
    __syncthreads();
    for (int off = 128; off > 0; off >>= 1) {
        if (t < off) sm[t] += sm[t + off];
        __syncthreads();
    }
    if (t == 0) part[blockIdx.x] = sm[0];
}

// exclusive scan of block partials (nb <= 256)
__global__ __launch_bounds__(256) void scanpart_k(int* __restrict__ part, int nb) {
    __shared__ int sm[256];
    int t = threadIdx.x;
    int v = (t < nb) ? part[t] : 0;
    sm[t] = v;
    __syncthreads();
    for (int off = 1; off < 256; off <<= 1) {
        int u = (t >= off) ? sm[t - off] : 0;
        __syncthreads();
        sm[t] += u;
        __syncthreads();
    }
    if (t < nb) part[t] = sm[t] - v;   // exclusive
}

// local scan + write rowptr/cursor, fused dinv
__global__ __launch_bounds__(256) void rowptr_k(const int* __restrict__ deg, const int* __restrict__ part,
                                                int* __restrict__ rowptr, int* __restrict__ cursor,
                                                float* __restrict__ dinv, int n) {
    __shared__ int sm[256];
    int t = threadIdx.x;
    int base = blockIdx.x * 1024 + t * 4;
    int d[4]; int s = 0;
#pragma unroll
    for (int j = 0; j < 4; ++j) { int idx = base + j; d[j] = (idx < n) ? deg[idx] : 0; s += d[j]; }
    sm[t] = s;
    __syncthreads();
    for (int off = 1; off < 256; off <<= 1) {
        int u = (t >= off) ? sm[t - off] : 0;
        __syncthreads();
        sm[t] += u;
        __syncthreads();
    }
    int ex = part[blockIdx.x] + sm[t] - s;
#pragma unroll
    for (int j = 0; j < 4; ++j) {
        int idx = base + j;
        if (idx < n) {
            rowptr[idx] = ex; cursor[idx] = ex;
            dinv[idx] = rsqrtf(fmaxf((float)d[j], 1.0f));
        }
        ex += d[j];
    }
    if (blockIdx.x == gridDim.x - 1 && t == 255) rowptr[n] = part[blockIdx.x] + sm[255];
}

// scatter edges into CSR (csrc only; dinv looked up in spmm)
__global__ __launch_bounds__(256) void scatter_k(const int* __restrict__ src, const int* __restrict__ dst,
                                                 int* __restrict__ cursor, int* __restrict__ csrc, int e) {
    int i = blockIdx.x * 256 + threadIdx.x;
    if (i < e) {
        int p = atomicAdd(&cursor[dst[i]], 1);
        csrc[p] = src[i];
    }
}

// ---------------- SpMM (normalized adjacency), bf16 rows, CSR by dst ----------------
// out[d][:] = dinv[d] * sum_{s in in(d)} dinv[s] * x[s][:]
// wave = 4 groups x 16 lanes; group g takes every-4th edge; lane loads uint4 (8 bf16 cols).
// x2 unroll -> 8 independent 256B row gathers in flight per wave.

__global__ __launch_bounds__(256) void spmm_bf_k(const unsigned short* __restrict__ x, const int* __restrict__ rowptr,
                                                 const int* __restrict__ csrc, const float* __restrict__ dinv,
                                                 unsigned short* __restrict__ out, int n) {
    int lane = threadIdx.x & 63;
    int wave = threadIdx.x >> 6;
    int node = blockIdx.x * 4 + wave;
    if (node >= n) return;
    int g = lane >> 4;        // edge group 0..3
    int c = lane & 15;        // uint4 column index: bf16 cols c*8 .. c*8+7
    int beg = rowptr[node], end = rowptr[node + 1];
    float acc[8];
#pragma unroll
    for (int j = 0; j < 8; ++j) acc[j] = 0.f;

    int i = beg + g;
    for (; i + 4 < end; i += 8) {
        int s0 = csrc[i], s1 = csrc[i + 4];
        float w0 = dinv[s0], w1 = dinv[s1];
        uint4 v0 = ((const uint4*)(x + (size_t)s0 * 128))[c];
        uint4 v1 = ((const uint4*)(x + (size_t)s1 * 128))[c];
        acc[0] += w0 * bflo(v0.x); acc[1] += w0 * bfhi(v0.x);
        acc[2] += w0 * bflo(v0.y); acc[3] += w0 * bfhi(v0.y);
        acc[4] += w0 * bflo(v0.z); acc[5] += w0 * bfhi(v0.z);
        acc[6] += w0 * bflo(v0.w); acc[7] += w0 * bfhi(v0.w);
        acc[0] += w1 * bflo(v1.x); acc[1] += w1 * bfhi(v1.x);
        acc[2] += w1 * bflo(v1.y); acc[3] += w1 * bfhi(v1.y);
        acc[4] += w1 * bflo(v1.z); acc[5] += w1 * bfhi(v1.z);
        acc[6] += w1 * bflo(v1.w); acc[7] += w1 * bfhi(v1.w);
    }
    if (i < end) {
        int s0 = csrc[i];
        float w0 = dinv[s0];
        uint4 v0 = ((const uint4*)(x + (size_t)s0 * 128))[c];
        acc[0] += w0 * bflo(v0.x); acc[1] += w0 * bfhi(v0.x);
        acc[2] += w0 * bflo(v0.y); acc[3] += w0 * bfhi(v0.y);
        acc[4] += w0 * bflo(v0.z); acc[5] += w0 * bfhi(v0.z);
        acc[6] += w0 * bflo(v0.w); acc[7] += w0 * bfhi(v0.w);
    }

    // combine the 4 edge-groups (lanes l, l^16, l^32, l^48 hold same columns)
#pragma unroll
    for (int j = 0; j < 8; ++j) {
        acc[j] += __shfl_xor(acc[j], 16, 64);
        acc[j] += __shfl_xor(acc[j], 32, 64);
    }

    float dd = dinv[node];
    if (g == 0) {
        uint4 o;
        o.x = packbf(acc[0] * dd, acc[1] * dd);
        o.y = packbf(acc[2] * dd, acc[3] * dd);
        o.z = packbf(acc[4] * dd, acc[5] * dd);
        o.w = packbf(acc[6] * dd, acc[7] * dd);
        ((uint4*)(out + (size_t)node * 128))[c] = o;
    }
}

// ---------------- weight pack into MFMA B-fragment order (bf16) ----------------
// wpack layout: [(ks*NF + f)*512 + lane*8 + j] = W'[ks*32 + (lane>>4)*8 + j][f*16 + (lane&15)]
// cheb mode: W' = [W0 - W2 ; -W1 ; 2*W2]  (K=384); else plain [K][N] row-major.

__global__ __launch_bounds__(256) void pack_w_k(const float* __restrict__ W, unsigned short* __restrict__ out,
                                                int K, int N, int cheb) {
    int id = blockIdx.x * 256 + threadIdx.x;
    int total = (K / 32) * (N / 16) * 64;
    if (id >= total) return;
    int lane = id & 63;
    int t2 = id >> 6;
    int nf = N / 16;
    int f = t2 % nf;
    int ks = t2 / nf;
    int col = f * 16 + (lane & 15);
    int kbase = ks * 32 + ((lane >> 4) * 8);
    for (int j = 0; j < 8; ++j) {
        int kg = kbase + j;
        float v;
        if (cheb) {
            int t = kg >> 7, kk = kg & 127;
            const float* W0 = W;
            const float* Wb = W + 16384;
            const float* Wc = W + 32768;
            float w0 = W0[kk * 128 + col], wb = Wb[kk * 128 + col], wc = Wc[kk * 128 + col];
            v = (t == 0) ? (w0 - wc) : (t == 1) ? (-wb) : (2.0f * wc);
        } else {
            v = W[(size_t)kg * N + col];
        }
        out[(size_t)id * 8 + j] = f2bf(v);
    }
}

// ---------------- MFMA GEMM: C[n x NF*16] = [s0|s1|s2](bf16) @ Wpack + bias ----------------

template<int KSTEPS, int NF, bool RELU, bool RES, bool OUTF32>
__global__ __launch_bounds__(256) void gemm_k(const unsigned short* __restrict__ s0,
                                              const unsigned short* __restrict__ s1,
                                              const unsigned short* __restrict__ s2,
                                              const unsigned short* __restrict__ wp,
                                              const float* __restrict__ bias,
                                              const unsigned short* __restrict__ resid,
                                              void* __restrict__ outv, int n) {
    int lane = threadIdx.x & 63;
    int wave = threadIdx.x >> 6;
    int row0 = blockIdx.x * 64 + wave * 16;
    if (row0 >= n) return;
    int rowA = row0 + (lane & 15);
    if (rowA >= n) rowA = n - 1;           // clamp reads; writes are guarded below
    int kg = (lane >> 4) * 8;

    f32x4 acc[NF];
#pragma unroll
    for (int f = 0; f < NF; ++f) acc[f] = (f32x4)(0.0f);

#pragma unroll
    for (int ks = 0; ks < KSTEPS; ++ks) {
        const unsigned short* sp;
        int kk;
        if (KSTEPS == 12) {
            sp = (ks < 4) ? s0 : ((ks < 8) ? s1 : s2);
            kk = (ks & 3) * 32 + kg;
        } else {
            sp = s0;
            kk = ks * 32 + kg;
        }
        short8 a = *(const short8*)(sp + (size_t)rowA * 128 + kk);
#pragma unroll
        for (int f = 0; f < NF; ++f) {
            short8 b = *(const short8*)(wp + ((size_t)(ks * NF + f) * 512 + lane * 8));
            acc[f] = __builtin_amdgcn_mfma_f32_16x16x32_bf16(a, b, acc[f], 0, 0, 0);
        }
    }

    int colb = lane & 15;
    int rowD = row0 + ((lane >> 4) << 2);
#pragma unroll
    for (int f = 0; f < NF; ++f) {
        int c = f * 16 + colb;
        float bv = bias[c];
#pragma unroll
        for (int r = 0; r < 4; ++r) {
            int row = rowD + r;
            if (row >= n) continue;
            float v = acc[f][r] + bv;
            if (RELU) v = fmaxf(v, 0.0f);
            if (RES) v += bf2f(resid[(size_t)row * 128 + c]);
            if (OUTF32) ((float*)outv)[(size_t)row * (NF * 16) + c] = v;
            else        ((unsigned short*)outv)[(size_t)row * (NF * 16) + c] = f2bf(v);
        }
    }
}

// ---------------- fused MLP: out = relu(x@mw1+mb1)@mw2 + mb2 ----------------
// Stage t = relu(x@mw1+mb1) (64x128 bf16) in XOR-swizzled LDS, then GEMM2 from LDS.

__global__ __launch_bounds__(256) void mlp_fused_k(const unsigned short* __restrict__ x,
                                                   const unsigned short* __restrict__ wp1,
                                                   const float* __restrict__ mb1,
                                                   const unsigned short* __restrict__ wp2,
                                                   const float* __restrict__ mb2,
                                                   float* __restrict__ out, int n) {
    __shared__ unsigned short tlds[64 * 128];   // 16 KiB
    int lane = threadIdx.x & 63;
    int wave = threadIdx.x >> 6;
    int row0 = blockIdx.x * 64 + wave * 16;
    int rowA = row0 + (lane & 15);
    if (rowA >= n) rowA = n - 1;
    int kg = (lane >> 4) * 8;
    int colb = lane & 15;

    // GEMM1: t = relu(x@mw1 + mb1)
    f32x4 acc[8];
#pragma unroll
    for (int f = 0; f < 8; ++f) acc[f] = (f32x4)(0.0f);
#pragma unroll
    for (int ks = 0; ks < 4; ++ks) {
        short8 a = *(const short8*)(x + (size_t)rowA * 128 + ks * 32 + kg);
#pragma unroll
        for (int f = 0; f < 8; ++f) {
            short8 b = *(const short8*)(wp1 + ((size_t)(ks * 8 + f) * 512 + lane * 8));
            acc[f] = __builtin_amdgcn_mfma_f32_16x16x32_bf16(a, b, acc[f], 0, 0, 0);
        }
    }
    int lrowD = wave * 16 + ((lane >> 4) << 2);
#pragma unroll
    for (int f = 0; f < 8; ++f) {
        int c = f * 16 + colb;
        float bv = mb1[c];
#pragma unroll
        for (int r = 0; r < 4; ++r) {
            int lrow = lrowD + r;
            float v = fmaxf(acc[f][r] + bv, 0.0f);
            int byte = lrow * 256 + c * 2;
            byte ^= ((lrow & 7) << 4);
            *(unsigned short*)((char*)tlds + byte) = f2bf(v);
        }
    }
    __syncthreads();

    // GEMM2: out = t@mw2 + mb2 (N=64)
    f32x4 acc2[4];
#pragma unroll
    for (int f = 0; f < 4; ++f) acc2[f] = (f32x4)(0.0f);
    int lrowA = wave * 16 + (lane & 15);
#pragma unroll
    for (int ks = 0; ks < 4; ++ks) {
        int byte = lrowA * 256 + (ks * 32 + kg) * 2;
        byte ^= ((lrowA & 7) << 4);
        short8 a = *(const short8*)((const char*)tlds + byte);
#pragma unroll
        for (int f = 0; f < 4; ++f) {
            short8 b = *(const short8*)(wp2 + ((size_t)(ks * 4 + f) * 512 + lane * 8));
            acc2[f] = __builtin_amdgcn_mfma_f32_16x16x32_bf16(a, b, acc2[f], 0, 0, 0);
        }
    }
    int rowD = row0 + ((lane >> 4) << 2);
#pragma unroll
    for (int f = 0; f < 4; ++f) {
        int c = f * 16 + colb;
        float bv = mb2[c];
#pragma unroll
        for (int r = 0; r < 4; ++r) {
            int row = rowD + r;
            if (row >= n) continue;
            out[(size_t)row * 64 + c] = acc2[f][r] + bv;
        }
    }
}

// ---------------- BatchNorm (training-mode batch stats) on bf16 buffer ----------------

__global__ __launch_bounds__(256) void bn_stats_k(const unsigned short* __restrict__ x, float* __restrict__ gsum,
                                                  float* __restrict__ gsqs, int n) {
    __shared__ float s1[256], s2[256];
    int c = threadIdx.x & 127;
    int h = threadIdx.x >> 7;
    int r0 = blockIdx.x * 256;
    int rend = r0 + 256; if (rend > n) rend = n;
    float a = 0.f, b = 0.f;
    for (int r = r0 + h; r < rend; r += 2) {
        float v = bf2f(x[(size_t)r * 128 + c]);
        a += v; b += v * v;
    }
    s1[threadIdx.x] = a; s2[threadIdx.x] = b;
    __syncthreads();
    if (threadIdx.x < 128) {
        a = s1[threadIdx.x] + s1[threadIdx.x + 128];
        b = s2[threadIdx.x] + s2[threadIdx.x + 128];
        atomicAdd(&gsum[c], a);
        atomicAdd(&gsqs[c], b);
    }
}

__global__ __launch_bounds__(256) void bn_apply_k(unsigned short* __restrict__ x, const float* __restrict__ gsum,
                                                  const float* __restrict__ gsqs, const float* __restrict__ gamma,
                                                  const float* __restrict__ beta, int n, float inv_n) {
    int i = blockIdx.x * 256 + threadIdx.x;   // over n*32 uint2 (4 bf16 each)
    if (i >= n * 32) return;
    int c4 = (i & 31) * 4;
    uint2 p = ((uint2*)x)[i];
    float f[4] = { bflo(p.x), bfhi(p.x), bflo(p.y), bfhi(p.y) };
#pragma unroll
    for (int j = 0; j < 4; ++j) {
        int c = c4 + j;
        float mu = gsum[c] * inv_n;
        float var = gsqs[c] * inv_n - mu * mu;
        float sc = rsqrtf(var + 1e-5f) * gamma[c];
        f[j] = (f[j] - mu) * sc + beta[c];
    }
    p.x = packbf(f[0], f[1]);
    p.y = packbf(f[2], f[3]);
    ((uint2*)x)[i] = p;
}

// ---------------- launch ----------------

extern "C" void kernel_launch(void* const* d_in, const int* in_sizes, int n_in,
                              void* d_out, int out_size, void* d_ws, size_t ws_size,
                              hipStream_t stream) {
    const float* feat  = (const float*)d_in[0];
    const int*   src   = (const int*)d_in[1];
    const int*   dst   = (const int*)d_in[2];
    const float* W1    = (const float*)d_in[3];
    const float* b1    = (const float*)d_in[4];
    const float* W2    = (const float*)d_in[5];
    const float* b2    = (const float*)d_in[6];
    const float* W3    = (const float*)d_in[7];
    const float* b3    = (const float*)d_in[8];
    const float* gamma = (const float*)d_in[9];
    const float* beta  = (const float*)d_in[10];
    const float* mw1   = (const float*)d_in[11];
    const float* mb1   = (const float*)d_in[12];
    const float* mw2   = (const float*)d_in[13];
    const float* mb2   = (const float*)d_in[14];
    float* outp = (float*)d_out;

    const int n = in_sizes[0] / 128;
    const int e = in_sizes[1];

    char* w = (char*)d_ws;
    auto alloc = [&](size_t bytes) -> void* {
        void* p = (void*)w;
        w += (bytes + 255) & ~(size_t)255;
        return p;
    };
    unsigned short* featb = (unsigned short*)alloc((size_t)n * 128 * 2);
    unsigned short* buf0  = (unsigned short*)alloc((size_t)n * 128 * 2);
    unsigned short* buf1  = (unsigned short*)alloc((size_t)n * 128 * 2);
    unsigned short* buf2  = (unsigned short*)alloc((size_t)n * 128 * 2);
    unsigned short* buf3  = (unsigned short*)alloc((size_t)n * 128 * 2);
    int*   deg    = (int*)alloc((size_t)n * 4);
    float* dinv   = (float*)alloc((size_t)n * 4);
    int*   rowptr = (int*)alloc((size_t)(n + 1) * 4);
    int*   cursor = (int*)alloc((size_t)n * 4);
    int*   csrc   = (int*)alloc((size_t)e * 4);
    int*   part   = (int*)alloc(256 * 4);
    unsigned short* wp1  = (unsigned short*)alloc(12 * 8 * 512 * 2);
    unsigned short* wp2  = (unsigned short*)alloc(12 * 8 * 512 * 2);
    unsigned short* wp3  = (unsigned short*)alloc(12 * 8 * 512 * 2);
    unsigned short* wpm1 = (unsigned short*)alloc(4 * 8 * 512 * 2);
    unsigned short* wpm2 = (unsigned short*)alloc(4 * 4 * 512 * 2);
    float* gsum = (float*)alloc(128 * 4);
    float* gsqs = (float*)alloc(128 * 4);

    const int gE = (e + 255) / 256;
    const int gGemm = (n + 63) / 64;
    const int gSpmm = (n + 3) / 4;
    const int gBnS = (n + 255) / 256;
    const int gBnA = (n * 32 + 255) / 256;
    const int nb = (n + 1023) / 1024;

    // feat -> bf16
    cast_k<<<(n * 32 + 255) / 256, 256, 0, stream>>>(feat, featb, n * 32);

    // degree + CSR (parallel scan) + dinv
    hipMemsetAsync(deg, 0, (size_t)n * 4, stream);
    deg_count_k<<<gE, 256, 0, stream>>>(dst, deg, e);
    partial_k<<<nb, 256, 0, stream>>>(deg, part, n);
    scanpart_k<<<1, 256, 0, stream>>>(part, nb);
    rowptr_k<<<nb, 256, 0, stream>>>(deg, part, rowptr, cursor, dinv, n);
    scatter_k<<<gE, 256, 0, stream>>>(src, dst, cursor, csrc, e);

    // weight packs
    pack_w_k<<<(12 * 8 * 64 + 255) / 256, 256, 0, stream>>>(W1, wp1, 384, 128, 1);
    pack_w_k<<<(12 * 8 * 64 + 255) / 256, 256, 0, stream>>>(W2, wp2, 384, 128, 1);
    pack_w_k<<<(12 * 8 * 64 + 255) / 256, 256, 0, stream>>>(W3, wp3, 384, 128, 1);
    pack_w_k<<<(4 * 8 * 64 + 255) / 256, 256, 0, stream>>>(mw1, wpm1, 128, 128, 0);
    pack_w_k<<<(4 * 4 * 64 + 255) / 256, 256, 0, stream>>>(mw2, wpm2, 128, 64, 0);

    // Layer 1: cheb(features, W1) -> relu -> buf0
    spmm_bf_k<<<gSpmm, 256, 0, stream>>>(featb, rowptr, csrc, dinv, buf1, n);
    spmm_bf_k<<<gSpmm, 256, 0, stream>>>(buf1, rowptr, csrc, dinv, buf2, n);
    gemm_k<12, 8, true, false, false><<<gGemm, 256, 0, stream>>>(featb, buf1, buf2, wp1, b1, nullptr, buf0, n);

    // BatchNorm on buf0 (in place)
    hipMemsetAsync(gsum, 0, 128 * 4, stream);
    hipMemsetAsync(gsqs, 0, 128 * 4, stream);
    bn_stats_k<<<gBnS, 256, 0, stream>>>(buf0, gsum, gsqs, n);
    bn_apply_k<<<gBnA, 256, 0, stream>>>(buf0, gsum, gsqs, gamma, beta, n, 1.0f / (float)n);

    // Layer 2a: cheb(buf0, W2) -> relu -> buf3
    spmm_bf_k<<<gSpmm, 256, 0, stream>>>(buf0, rowptr, csrc, dinv, buf1, n);
    spmm_bf_k<<<gSpmm, 256, 0, stream>>>(buf1, rowptr, csrc, dinv, buf2, n);
    gemm_k<12, 8, true, false, false><<<gGemm, 256, 0, stream>>>(buf0, buf1, buf2, wp2, b2, nullptr, buf3, n);

    // Layer 2b: cheb(buf3, W2) -> relu -> buf0
    spmm_bf_k<<<gSpmm, 256, 0, stream>>>(buf3, rowptr, csrc, dinv, buf1, n);
    spmm_bf_k<<<gSpmm, 256, 0, stream>>>(buf1, rowptr, csrc, dinv, buf2, n);
    gemm_k<12, 8, true, false, false><<<gGemm, 256, 0, stream>>>(buf3, buf1, buf2, wp2, b2, nullptr, buf0, n);

    // Layer 3: cheb(buf0, W3) -> relu -> + residual(buf0) -> buf3
    spmm_bf_k<<<gSpmm, 256, 0, stream>>>(buf0, rowptr, csrc, dinv, buf1, n);
    spmm_bf_k<<<gSpmm, 256, 0, stream>>>(buf1, rowptr, csrc, dinv, buf2, n);
    gemm_k<12, 8, true, true, false><<<gGemm, 256, 0, stream>>>(buf0, buf1, buf2, wp3, b3, buf0, buf3, n);

    // fused MLP: out = relu(buf3@mw1+mb1)@mw2 + mb2 (fp32 out)
    mlp_fused_k<<<gGemm, 256, 0, stream>>>(buf3, wpm1, mb1, wpm2, mb2, outp, n);
}

// Round 5
// 540.350 us; speedup vs baseline: 2.0211x; 1.0359x over previous
//
#include <hip/hip_runtime.h>
#include <hip/hip_bf16.h>

typedef __attribute__((ext_vector_type(4))) float f32x4;
typedef __attribute__((ext_vector_type(8))) short short8;

__device__ inline unsigned short f2bf(float f) {
    union { float f; unsigned int u; } v; v.f = f;
    unsigned int u = v.u;
    return (unsigned short)((u + 0x7fffu + ((u >> 16) & 1u)) >> 16);
}
__device__ inline float bf2f(unsigned short h) {
    union { unsigned int u; float f; } v; v.u = ((unsigned int)h) << 16; return v.f;
}
__device__ inline float bflo(unsigned int p) {
    union { unsigned int u; float f; } v; v.u = p << 16; return v.f;
}
__device__ inline float bfhi(unsigned int p) {
    union { unsigned int u; float f; } v; v.u = p & 0xffff0000u; return v.f;
}
__device__ inline unsigned int packbf(float a, float b) {
    return (unsigned int)f2bf(a) | ((unsigned int)f2bf(b) << 16);
}

// ---------------- fp32 -> bf16 cast ----------------

__global__ __launch_bounds__(256) void cast_k(const float* __restrict__ x, unsigned short* __restrict__ y, int n4) {
    int i = blockIdx.x * 256 + threadIdx.x;   // one f32x4 per thread
    if (i >= n4) return;
    f32x4 v = ((const f32x4*)x)[i];
    uint2 o; o.x = packbf(v[0], v[1]); o.y = packbf(v[2], v[3]);
    ((uint2*)y)[i] = o;
}

// ---------------- degree / CSR build (parallel scan) ----------------

__global__ __launch_bounds__(256) void deg_count_k(const int* __restrict__ dst, int* __restrict__ deg, int e) {
    int i = blockIdx.x * 256 + threadIdx.x;
    if (i < e) atomicAdd(&deg[dst[i]], 1);
}

// per-block (1024 elements) sums
__global__ __launch_bounds__(256) void partial_k(const int* __restrict__ deg, int* __restrict__ part, int n) {
    __shared__ int sm[256];
    int t = threadIdx.x;
    int base = blockIdx.x * 1024 + t * 4;
    int s = 0;
#pragma unroll
    for (int j = 0; j < 4; ++j) { int idx = base + j; if (idx < n) s += deg[idx]; }
    sm[t] = s;
    __syncthreads();
    for (int off = 128; off > 0; off >>= 1) {
        if (t < off) sm[t] += sm[t + off];
        __syncthreads();
    }
    if (t == 0) part[blockIdx.x] = sm[0];
}

// exclusive scan of block partials (nb <= 256)
__global__ __launch_bounds__(256) void scanpart_k(int* __restrict__ part, int nb) {
    __shared__ int sm[256];
    int t = threadIdx.x;
    int v = (t < nb) ? part[t] : 0;
    sm[t] = v;
    __syncthreads();
    for (int off = 1; off < 256; off <<= 1) {
        int u = (t >= off) ? sm[t - off] : 0;
        __syncthreads();
        sm[t] += u;
        __syncthreads();
    }
    if (t < nb) part[t] = sm[t] - v;   // exclusive
}

// local scan + write rowptr/cursor, fused dinv
__global__ __launch_bounds__(256) void rowptr_k(const int* __restrict__ deg, const int* __restrict__ part,
                                                int* __restrict__ rowptr, int* __restrict__ cursor,
                                                float* __restrict__ dinv, int n) {
    __shared__ int sm[256];
    int t = threadIdx.x;
    int base = blockIdx.x * 1024 + t * 4;
    int d[4]; int s = 0;
#pragma unroll
    for (int j = 0; j < 4; ++j) { int idx = base + j; d[j] = (idx < n) ? deg[idx] : 0; s += d[j]; }
    sm[t] = s;
    __syncthreads();
    for (int off = 1; off < 256; off <<= 1) {
        int u = (t >= off) ? sm[t - off] : 0;
        __syncthreads();
        sm[t] += u;
        __syncthreads();
    }
    int ex = part[blockIdx.x] + sm[t] - s;
#pragma unroll
    for (int j = 0; j < 4; ++j) {
        int idx = base + j;
        if (idx < n) {
            rowptr[idx] = ex; cursor[idx] = ex;
            dinv[idx] = rsqrtf(fmaxf((float)d[j], 1.0f));
        }
        ex += d[j];
    }
    if (blockIdx.x == gridDim.x - 1 && t == 255) rowptr[n] = part[blockIdx.x] + sm[255];
}

// scatter edges into CSR (csrc only; dinv looked up in spmm)
__global__ __launch_bounds__(256) void scatter_k(const int* __restrict__ src, const int* __restrict__ dst,
                                                 int* __restrict__ cursor, int* __restrict__ csrc, int e) {
    int i = blockIdx.x * 256 + threadIdx.x;
    if (i < e) {
        int p = atomicAdd(&cursor[dst[i]], 1);
        csrc[p] = src[i];
    }
}

// ---------------- SpMM (normalized adjacency), bf16 rows, CSR by dst ----------------
// out[d][:] = dinv[d] * sum_{s in in(d)} dinv[s] * x[s][:]
// wave = 4 groups x 16 lanes; group g takes every-4th edge, 4-deep unroll:
// 16 independent 256B row gathers in flight per wave.

__global__ __launch_bounds__(256) void spmm_bf_k(const unsigned short* __restrict__ x, const int* __restrict__ rowptr,
                                                 const int* __restrict__ csrc, const float* __restrict__ dinv,
                                                 unsigned short* __restrict__ out, int n) {
    int lane = threadIdx.x & 63;
    int wave = threadIdx.x >> 6;
    int node = blockIdx.x * 4 + wave;
    if (node >= n) return;
    int g = lane >> 4;        // edge group 0..3
    int c = lane & 15;        // uint4 column index: bf16 cols c*8 .. c*8+7
    int beg = rowptr[node], end = rowptr[node + 1];
    float acc[8];
#pragma unroll
    for (int j = 0; j < 8; ++j) acc[j] = 0.f;

    int i = beg + g;
    // 4-deep: edges i, i+4, i+8, i+12 all in flight
    for (; i + 12 < end; i += 16) {
        int s0 = csrc[i], s1 = csrc[i + 4], s2 = csrc[i + 8], s3 = csrc[i + 12];
        float w0 = dinv[s0], w1 = dinv[s1], w2 = dinv[s2], w3 = dinv[s3];
        uint4 v0 = ((const uint4*)(x + (size_t)s0 * 128))[c];
        uint4 v1 = ((const uint4*)(x + (size_t)s1 * 128))[c];
        uint4 v2 = ((const uint4*)(x + (size_t)s2 * 128))[c];
        uint4 v3 = ((const uint4*)(x + (size_t)s3 * 128))[c];
        acc[0] += w0 * bflo(v0.x); acc[1] += w0 * bfhi(v0.x);
        acc[2] += w0 * bflo(v0.y); acc[3] += w0 * bfhi(v0.y);
        acc[4] += w0 * bflo(v0.z); acc[5] += w0 * bfhi(v0.z);
        acc[6] += w0 * bflo(v0.w); acc[7] += w0 * bfhi(v0.w);
        acc[0] += w1 * bflo(v1.x); acc[1] += w1 * bfhi(v1.x);
        acc[2] += w1 * bflo(v1.y); acc[3] += w1 * bfhi(v1.y);
        acc[4] += w1 * bflo(v1.z); acc[5] += w1 * bfhi(v1.z);
        acc[6] += w1 * bflo(v1.w); acc[7] += w1 * bfhi(v1.w);
        acc[0] += w2 * bflo(v2.x); acc[1] += w2 * bfhi(v2.x);
        acc[2] += w2 * bflo(v2.y); acc[3] += w2 * bfhi(v2.y);
        acc[4] += w2 * bflo(v2.z); acc[5] += w2 * bfhi(v2.z);
        acc[6] += w2 * bflo(v2.w); acc[7] += w2 * bfhi(v2.w);
        acc[0] += w3 * bflo(v3.x); acc[1] += w3 * bfhi(v3.x);
        acc[2] += w3 * bflo(v3.y); acc[3] += w3 * bfhi(v3.y);
        acc[4] += w3 * bflo(v3.z); acc[5] += w3 * bfhi(v3.z);
        acc[6] += w3 * bflo(v3.w); acc[7] += w3 * bfhi(v3.w);
    }
    for (; i < end; i += 4) {
        int s0 = csrc[i];
        float w0 = dinv[s0];
        uint4 v0 = ((const uint4*)(x + (size_t)s0 * 128))[c];
        acc[0] += w0 * bflo(v0.x); acc[1] += w0 * bfhi(v0.x);
        acc[2] += w0 * bflo(v0.y); acc[3] += w0 * bfhi(v0.y);
        acc[4] += w0 * bflo(v0.z); acc[5] += w0 * bfhi(v0.z);
        acc[6] += w0 * bflo(v0.w); acc[7] += w0 * bfhi(v0.w);
    }

    // combine the 4 edge-groups (lanes l, l^16, l^32, l^48 hold same columns)
#pragma unroll
    for (int j = 0; j < 8; ++j) {
        acc[j] += __shfl_xor(acc[j], 16, 64);
        acc[j] += __shfl_xor(acc[j], 32, 64);
    }

    float dd = dinv[node];
    if (g == 0) {
        uint4 o;
        o.x = packbf(acc[0] * dd, acc[1] * dd);
        o.y = packbf(acc[2] * dd, acc[3] * dd);
        o.z = packbf(acc[4] * dd, acc[5] * dd);
        o.w = packbf(acc[6] * dd, acc[7] * dd);
        ((uint4*)(out + (size_t)node * 128))[c] = o;
    }
}

// ---------------- weight pack into MFMA B-fragment order (bf16) ----------------
// wpack layout: [(ks*NF + f)*512 + lane*8 + j] = W'[ks*32 + (lane>>4)*8 + j][f*16 + (lane&15)]
// cheb mode: W' = [W0 - W2 ; -W1 ; 2*W2]  (K=384); else plain [K][N] row-major.

__global__ __launch_bounds__(256) void pack_w_k(const float* __restrict__ W, unsigned short* __restrict__ out,
                                                int K, int N, int cheb) {
    int id = blockIdx.x * 256 + threadIdx.x;
    int total = (K / 32) * (N / 16) * 64;
    if (id >= total) return;
    int lane = id & 63;
    int t2 = id >> 6;
    int nf = N / 16;
    int f = t2 % nf;
    int ks = t2 / nf;
    int col = f * 16 + (lane & 15);
    int kbase = ks * 32 + ((lane >> 4) * 8);
    for (int j = 0; j < 8; ++j) {
        int kg = kbase + j;
        float v;
        if (cheb) {
            int t = kg >> 7, kk = kg & 127;
            const float* W0 = W;
            const float* Wb = W + 16384;
            const float* Wc = W + 32768;
            float w0 = W0[kk * 128 + col], wb = Wb[kk * 128 + col], wc = Wc[kk * 128 + col];
            v = (t == 0) ? (w0 - wc) : (t == 1) ? (-wb) : (2.0f * wc);
        } else {
            v = W[(size_t)kg * N + col];
        }
        out[(size_t)id * 8 + j] = f2bf(v);
    }
}

// ---------------- MFMA GEMM: C[n x NF*16] = [s0|s1|s2](bf16) @ Wpack + bias ----------------

template<int KSTEPS, int NF, bool RELU, bool RES, bool OUTF32>
__global__ __launch_bounds__(256) void gemm_k(const unsigned short* __restrict__ s0,
                                              const unsigned short* __restrict__ s1,
                                              const unsigned short* __restrict__ s2,
                                              const unsigned short* __restrict__ wp,
                                              const float* __restrict__ bias,
                                              const unsigned short* __restrict__ resid,
                                              void* __restrict__ outv, int n) {
    int lane = threadIdx.x & 63;
    int wave = threadIdx.x >> 6;
    int row0 = blockIdx.x * 64 + wave * 16;
    if (row0 >= n) return;
    int rowA = row0 + (lane & 15);
    if (rowA >= n) rowA = n - 1;           // clamp reads; writes are guarded below
    int kg = (lane >> 4) * 8;

    f32x4 acc[NF];
#pragma unroll
    for (int f = 0; f < NF; ++f) acc[f] = (f32x4)(0.0f);

#pragma unroll
    for (int ks = 0; ks < KSTEPS; ++ks) {
        const unsigned short* sp;
        int kk;
        if (KSTEPS == 12) {
            sp = (ks < 4) ? s0 : ((ks < 8) ? s1 : s2);
            kk = (ks & 3) * 32 + kg;
        } else {
            sp = s0;
            kk = ks * 32 + kg;
        }
        short8 a = *(const short8*)(sp + (size_t)rowA * 128 + kk);
#pragma unroll
        for (int f = 0; f < NF; ++f) {
            short8 b = *(const short8*)(wp + ((size_t)(ks * NF + f) * 512 + lane * 8));
            acc[f] = __builtin_amdgcn_mfma_f32_16x16x32_bf16(a, b, acc[f], 0, 0, 0);
        }
    }

    int colb = lane & 15;
    int rowD = row0 + ((lane >> 4) << 2);
#pragma unroll
    for (int f = 0; f < NF; ++f) {
        int c = f * 16 + colb;
        float bv = bias[c];
#pragma unroll
        for (int r = 0; r < 4; ++r) {
            int row = rowD + r;
            if (row >= n) continue;
            float v = acc[f][r] + bv;
            if (RELU) v = fmaxf(v, 0.0f);
            if (RES) v += bf2f(resid[(size_t)row * 128 + c]);
            if (OUTF32) ((float*)outv)[(size_t)row * (NF * 16) + c] = v;
            else        ((unsigned short*)outv)[(size_t)row * (NF * 16) + c] = f2bf(v);
        }
    }
}

// ---------------- fused MLP: out = relu(x@mw1+mb1)@mw2 + mb2 ----------------
// Stage t = relu(x@mw1+mb1) (64x128 bf16) in XOR-swizzled LDS, then GEMM2 from LDS.

__global__ __launch_bounds__(256) void mlp_fused_k(const unsigned short* __restrict__ x,
                                                   const unsigned short* __restrict__ wp1,
                                                   const float* __restrict__ mb1,
                                                   const unsigned short* __restrict__ wp2,
                                                   const float* __restrict__ mb2,
                                                   float* __restrict__ out, int n) {
    __shared__ unsigned short tlds[64 * 128];   // 16 KiB
    int lane = threadIdx.x & 63;
    int wave = threadIdx.x >> 6;
    int row0 = blockIdx.x * 64 + wave * 16;
    int rowA = row0 + (lane & 15);
    if (rowA >= n) rowA = n - 1;
    int kg = (lane >> 4) * 8;
    int colb = lane & 15;

    // GEMM1: t = relu(x@mw1 + mb1)
    f32x4 acc[8];
#pragma unroll
    for (int f = 0; f < 8; ++f) acc[f] = (f32x4)(0.0f);
#pragma unroll
    for (int ks = 0; ks < 4; ++ks) {
        short8 a = *(const short8*)(x + (size_t)rowA * 128 + ks * 32 + kg);
#pragma unroll
        for (int f = 0; f < 8; ++f) {
            short8 b = *(const short8*)(wp1 + ((size_t)(ks * 8 + f) * 512 + lane * 8));
            acc[f] = __builtin_amdgcn_mfma_f32_16x16x32_bf16(a, b, acc[f], 0, 0, 0);
        }
    }
    int lrowD = wave * 16 + ((lane >> 4) << 2);
#pragma unroll
    for (int f = 0; f < 8; ++f) {
        int c = f * 16 + colb;
        float bv = mb1[c];
#pragma unroll
        for (int r = 0; r < 4; ++r) {
            int lrow = lrowD + r;
            float v = fmaxf(acc[f][r] + bv, 0.0f);
            int byte = lrow * 256 + c * 2;
            byte ^= ((lrow & 7) << 4);
            *(unsigned short*)((char*)tlds + byte) = f2bf(v);
        }
    }
    __syncthreads();

    // GEMM2: out = t@mw2 + mb2 (N=64)
    f32x4 acc2[4];
#pragma unroll
    for (int f = 0; f < 4; ++f) acc2[f] = (f32x4)(0.0f);
    int lrowA = wave * 16 + (lane & 15);
#pragma unroll
    for (int ks = 0; ks < 4; ++ks) {
        int byte = lrowA * 256 + (ks * 32 + kg) * 2;
        byte ^= ((lrowA & 7) << 4);
        short8 a = *(const short8*)((const char*)tlds + byte);
#pragma unroll
        for (int f = 0; f < 4; ++f) {
            short8 b = *(const short8*)(wp2 + ((size_t)(ks * 4 + f) * 512 + lane * 8));
            acc2[f] = __builtin_amdgcn_mfma_f32_16x16x32_bf16(a, b, acc2[f], 0, 0, 0);
        }
    }
    int rowD = row0 + ((lane >> 4) << 2);
#pragma unroll
    for (int f = 0; f < 4; ++f) {
        int c = f * 16 + colb;
        float bv = mb2[c];
#pragma unroll
        for (int r = 0; r < 4; ++r) {
            int row = rowD + r;
            if (row >= n) continue;
            out[(size_t)row * 64 + c] = acc2[f][r] + bv;
        }
    }
}

// ---------------- BatchNorm (training-mode batch stats) on bf16 buffer ----------------

__global__ __launch_bounds__(256) void bn_stats_k(const unsigned short* __restrict__ x, float* __restrict__ gsum,
                                                  float* __restrict__ gsqs, int n) {
    __shared__ float s1[256], s2[256];
    int c = threadIdx.x & 127;
    int h = threadIdx.x >> 7;
    int r0 = blockIdx.x * 256;
    int rend = r0 + 256; if (rend > n) rend = n;
    float a = 0.f, b = 0.f;
    for (int r = r0 + h; r < rend; r += 2) {
        float v = bf2f(x[(size_t)r * 128 + c]);
        a += v; b += v * v;
    }
    s1[threadIdx.x] = a; s2[threadIdx.x] = b;
    __syncthreads();
    if (threadIdx.x < 128) {
        a = s1[threadIdx.x] + s1[threadIdx.x + 128];
        b = s2[threadIdx.x] + s2[threadIdx.x + 128];
        atomicAdd(&gsum[c], a);
        atomicAdd(&gsqs[c], b);
    }
}

__global__ __launch_bounds__(256) void bn_apply_k(unsigned short* __restrict__ x, const float* __restrict__ gsum,
                                                  const float* __restrict__ gsqs, const float* __restrict__ gamma,
                                                  const float* __restrict__ beta, int n, float inv_n) {
    int i = blockIdx.x * 256 + threadIdx.x;   // over n*32 uint2 (4 bf16 each)
    if (i >= n * 32) return;
    int c4 = (i & 31) * 4;
    uint2 p = ((uint2*)x)[i];
    float f[4] = { bflo(p.x), bfhi(p.x), bflo(p.y), bfhi(p.y) };
#pragma unroll
    for (int j = 0; j < 4; ++j) {
        int c = c4 + j;
        float mu = gsum[c] * inv_n;
        float var = gsqs[c] * inv_n - mu * mu;
        float sc = rsqrtf(var + 1e-5f) * gamma[c];
        f[j] = (f[j] - mu) * sc + beta[c];
    }
    p.x = packbf(f[0], f[1]);
    p.y = packbf(f[2], f[3]);
    ((uint2*)x)[i] = p;
}

// ---------------- launch ----------------

extern "C" void kernel_launch(void* const* d_in, const int* in_sizes, int n_in,
                              void* d_out, int out_size, void* d_ws, size_t ws_size,
                              hipStream_t stream) {
    const float* feat  = (const float*)d_in[0];
    const int*   src   = (const int*)d_in[1];
    const int*   dst   = (const int*)d_in[2];
    const float* W1    = (const float*)d_in[3];
    const float* b1    = (const float*)d_in[4];
    const float* W2    = (const float*)d_in[5];
    const float* b2    = (const float*)d_in[6];
    const float* W3    = (const float*)d_in[7];
    const float* b3    = (const float*)d_in[8];
    const float* gamma = (const float*)d_in[9];
    const float* beta  = (const float*)d_in[10];
    const float* mw1   = (const float*)d_in[11];
    const float* mb1   = (const float*)d_in[12];
    const float* mw2   = (const float*)d_in[13];
    const float* mb2   = (const float*)d_in[14];
    float* outp = (float*)d_out;

    const int n = in_sizes[0] / 128;
    const int e = in_sizes[1];

    char* w = (char*)d_ws;
    auto alloc = [&](size_t bytes) -> void* {
        void* p = (void*)w;
        w += (bytes + 255) & ~(size_t)255;
        return p;
    };
    unsigned short* featb = (unsigned short*)alloc((size_t)n * 128 * 2);
    unsigned short* buf0  = (unsigned short*)alloc((size_t)n * 128 * 2);
    unsigned short* buf1  = (unsigned short*)alloc((size_t)n * 128 * 2);
    unsigned short* buf2  = (unsigned short*)alloc((size_t)n * 128 * 2);
    unsigned short* buf3  = (unsigned short*)alloc((size_t)n * 128 * 2);
    int*   deg    = (int*)alloc((size_t)n * 4);
    float* dinv   = (float*)alloc((size_t)n * 4);
    int*   rowptr = (int*)alloc((size_t)(n + 1) * 4);
    int*   cursor = (int*)alloc((size_t)n * 4);
    int*   csrc   = (int*)alloc((size_t)e * 4);
    int*   part   = (int*)alloc(256 * 4);
    unsigned short* wp1  = (unsigned short*)alloc(12 * 8 * 512 * 2);
    unsigned short* wp2  = (unsigned short*)alloc(12 * 8 * 512 * 2);
    unsigned short* wp3  = (unsigned short*)alloc(12 * 8 * 512 * 2);
    unsigned short* wpm1 = (unsigned short*)alloc(4 * 8 * 512 * 2);
    unsigned short* wpm2 = (unsigned short*)alloc(4 * 4 * 512 * 2);
    float* gsum = (float*)alloc(128 * 4);
    float* gsqs = (float*)alloc(128 * 4);

    const int gE = (e + 255) / 256;
    const int gGemm = (n + 63) / 64;
    const int gSpmm = (n + 3) / 4;
    const int gBnS = (n + 255) / 256;
    const int gBnA = (n * 32 + 255) / 256;
    const int nb = (n + 1023) / 1024;

    // feat -> bf16
    cast_k<<<(n * 32 + 255) / 256, 256, 0, stream>>>(feat, featb, n * 32);

    // degree + CSR (parallel scan) + dinv
    hipMemsetAsync(deg, 0, (size_t)n * 4, stream);
    deg_count_k<<<gE, 256, 0, stream>>>(dst, deg, e);
    partial_k<<<nb, 256, 0, stream>>>(deg, part, n);
    scanpart_k<<<1, 256, 0, stream>>>(part, nb);
    rowptr_k<<<nb, 256, 0, stream>>>(deg, part, rowptr, cursor, dinv, n);
    scatter_k<<<gE, 256, 0, stream>>>(src, dst, cursor, csrc, e);

    // weight packs
    pack_w_k<<<(12 * 8 * 64 + 255) / 256, 256, 0, stream>>>(W1, wp1, 384, 128, 1);
    pack_w_k<<<(12 * 8 * 64 + 255) / 256, 256, 0, stream>>>(W2, wp2, 384, 128, 1);
    pack_w_k<<<(12 * 8 * 64 + 255) / 256, 256, 0, stream>>>(W3, wp3, 384, 128, 1);
    pack_w_k<<<(4 * 8 * 64 + 255) / 256, 256, 0, stream>>>(mw1, wpm1, 128, 128, 0);
    pack_w_k<<<(4 * 4 * 64 + 255) / 256, 256, 0, stream>>>(mw2, wpm2, 128, 64, 0);

    // Layer 1: cheb(features, W1) -> relu -> buf0
    spmm_bf_k<<<gSpmm, 256, 0, stream>>>(featb, rowptr, csrc, dinv, buf1, n);
    spmm_bf_k<<<gSpmm, 256, 0, stream>>>(buf1, rowptr, csrc, dinv, buf2, n);
    gemm_k<12, 8, true, false, false><<<gGemm, 256, 0, stream>>>(featb, buf1, buf2, wp1, b1, nullptr, buf0, n);

    // BatchNorm on buf0 (in place)
    hipMemsetAsync(gsum, 0, 128 * 4, stream);
    hipMemsetAsync(gsqs, 0, 128 * 4, stream);
    bn_stats_k<<<gBnS, 256, 0, stream>>>(buf0, gsum, gsqs, n);
    bn_apply_k<<<gBnA, 256, 0, stream>>>(buf0, gsum, gsqs, gamma, beta, n, 1.0f / (float)n);

    // Layer 2a: cheb(buf0, W2) -> relu -> buf3
    spmm_bf_k<<<gSpmm, 256, 0, stream>>>(buf0, rowptr, csrc, dinv, buf1, n);
    spmm_bf_k<<<gSpmm, 256, 0, stream>>>(buf1, rowptr, csrc, dinv, buf2, n);
    gemm_k<12, 8, true, false, false><<<gGemm, 256, 0, stream>>>(buf0, buf1, buf2, wp2, b2, nullptr, buf3, n);

    // Layer 2b: cheb(buf3, W2) -> relu -> buf0
    spmm_bf_k<<<gSpmm, 256, 0, stream>>>(buf3, rowptr, csrc, dinv, buf1, n);
    spmm_bf_k<<<gSpmm, 256, 0, stream>>>(buf1, rowptr, csrc, dinv, buf2, n);
    gemm_k<12, 8, true, false, false><<<gGemm, 256, 0, stream>>>(buf3, buf1, buf2, wp2, b2, nullptr, buf0, n);

    // Layer 3: cheb(buf0, W3) -> relu -> + residual(buf0) -> buf3
    spmm_bf_k<<<gSpmm, 256, 0, stream>>>(buf0, rowptr, csrc, dinv, buf1, n);
    spmm_bf_k<<<gSpmm, 256, 0, stream>>>(buf1, rowptr, csrc, dinv, buf2, n);
    gemm_k<12, 8, true, true, false><<<gGemm, 256, 0, stream>>>(buf0, buf1, buf2, wp3, b3, buf0, buf3, n);

    // fused MLP: out = relu(buf3@mw1+mb1)@mw2 + mb2 (fp32 out)
    mlp_fused_k<<<gGemm, 256, 0, stream>>>(buf3, wpm1, mb1, wpm2, mb2, outp, n);
}